// Round 6
// baseline (539.637 us; speedup 1.0000x reference)
//
#include <hip/hip_runtime.h>
#include <hip/hip_cooperative_groups.h>

namespace cg = cooperative_groups;

#define D_   256
#define UD_  48
#define NO_  80
#define T_   128
#define B_   2048

typedef __bf16 bf16x8 __attribute__((ext_vector_type(8)));
typedef float  f32x4  __attribute__((ext_vector_type(4)));
typedef unsigned short ushort_t;

static __device__ __forceinline__ ushort_t f2bf(float f){
  return __builtin_bit_cast(ushort_t, (__bf16)f);
}
static __device__ __forceinline__ float bf2f(ushort_t u){
  union { unsigned int i; float f; } c; c.i = ((unsigned int)u) << 16; return c.f;
}
static __device__ __forceinline__ f32x4 mfma16(bf16x8 a, bf16x8 b, f32x4 c){
  return __builtin_amdgcn_mfma_f32_16x16x32_bf16(a, b, c, 0, 0, 0);
}

// ---------------- fused prep + boundary scan (single cooperative kernel) ----------------
// 256 blocks x 256 thr. Phases separated by grid.sync():
// P0 init | P1..P6 Newton-Schulz (3 iters) | P7 VinvT/Lw/Cw/dVd | P8 w0+Lws+packA | P9 scan.
// Replaces 10 serial launches (round-5 analysis: prep+scan ~150us was the majority cost).

#define NS_MUL(Ap, Bp, Cp) do {                                                 \
  const float* Ar = (Ap) + bid*D_;                                              \
  float a0=0.f,a1=0.f,a2=0.f,a3=0.f;                                            \
  _Pragma("unroll 4")                                                           \
  for (int k = 0; k < D_; k += 4){                                              \
    a0 += Ar[k+0]*(Bp)[(k+0)*D_+tid]; a1 += Ar[k+1]*(Bp)[(k+1)*D_+tid];         \
    a2 += Ar[k+2]*(Bp)[(k+2)*D_+tid]; a3 += Ar[k+3]*(Bp)[(k+3)*D_+tid]; }       \
  (Cp)[bid*D_+tid] = (a0+a1)+(a2+a3); } while(0)

#define NS_UPD(Xp, Tp, Xn) do {                                                 \
  const float* Xr = (Xp) + bid*D_;                                              \
  float a0=0.f,a1=0.f,a2=0.f,a3=0.f;                                            \
  _Pragma("unroll 4")                                                           \
  for (int k = 0; k < D_; k += 4){                                              \
    a0 += Xr[k+0]*(Tp)[(k+0)*D_+tid]; a1 += Xr[k+1]*(Tp)[(k+1)*D_+tid];         \
    a2 += Xr[k+2]*(Tp)[(k+2)*D_+tid]; a3 += Xr[k+3]*(Tp)[(k+3)*D_+tid]; }       \
  (Xn)[bid*D_+tid] = 2.0f*Xr[tid] - ((a0+a1)+(a2+a3)); } while(0)

#define SCAN_STEP(UA, UB, UC, TT) do {                                          \
  union { ushort_t us[8]; bf16x8 v; } c0, c1;                                   \
  c0.us[0]=f2bf((UA).x); c0.us[1]=f2bf((UA).y); c0.us[2]=f2bf((UA).z); c0.us[3]=f2bf((UA).w); \
  c0.us[4]=f2bf((UB).x); c0.us[5]=f2bf((UB).y); c0.us[6]=f2bf((UB).z); c0.us[7]=f2bf((UB).w); \
  c1.us[0]=f2bf((UC).x); c1.us[1]=f2bf((UC).y); c1.us[2]=f2bf((UC).z); c1.us[3]=f2bf((UC).w); \
  c1.us[4]=0; c1.us[5]=0; c1.us[6]=0; c1.us[7]=0;                               \
  _Pragma("unroll")                                                             \
  for (int q = 0; q < 2; ++q){                                                  \
    f32x4 acc = {0.f,0.f,0.f,0.f};                                              \
    acc = mfma16(lwf[q*2+0], c0.v, acc);                                        \
    acc = mfma16(lwf[q*2+1], c1.v, acc);                                        \
    _Pragma("unroll")                                                           \
    for (int r = 0; r < 4; ++r) w[q*4+r] = lamr[q*4+r]*w[q*4+r] + acc[r];       \
  }                                                                             \
  if ((((TT) & 7) == 7) && ((TT) < T_-1)){                                      \
    const int c2 = ((TT)+1) >> 3;                                               \
    _Pragma("unroll")                                                           \
    for (int q = 0; q < 2; ++q){                                                \
      const int i = (itb+q)*16 + 4*lh;                                          \
      ushort4 o; o.x=f2bf(w[q*4+0]); o.y=f2bf(w[q*4+1]); o.z=f2bf(w[q*4+2]); o.w=f2bf(w[q*4+3]); \
      *(ushort4*)(Wchk + ((size_t)c2*B_ + row)*D_ + i) = o;                     \
    }                                                                           \
  }                                                                             \
} while(0)

__global__ void __launch_bounds__(256) k_prep(
    const float* __restrict__ V, const float* __restrict__ eig,
    const float* __restrict__ Lm, const float* __restrict__ Cmat,
    const float* __restrict__ Dmat, const float* __restrict__ dt,
    const float* __restrict__ z0, const float* __restrict__ U,
    float* __restrict__ Xa, float* __restrict__ Xb, float* __restrict__ Tt,
    float* __restrict__ Lw, float* __restrict__ Cw,
    float* __restrict__ lam, float* __restrict__ dVd,
    ushort_t* __restrict__ Af, ushort_t* __restrict__ Lws,
    ushort_t* __restrict__ Wchk){
  __shared__ float zr[8][256];
  cg::grid_group grid = cg::this_grid();
  const int bid = blockIdx.x, tid = threadIdx.x;

  // P0: init X0 = 2I - V; lam
  Xa[bid*D_ + tid] = (bid == tid ? 2.0f : 0.0f) - V[bid*D_ + tid];
  if (tid == 0) lam[bid] = 0.99f / (1.0f + expf(-eig[bid]));
  grid.sync();
  // P1..P6: Newton-Schulz, 3 iters -> Vinv = Xb
  NS_MUL(V, Xa, Tt);  grid.sync();
  NS_UPD(Xa, Tt, Xb); grid.sync();
  NS_MUL(V, Xb, Tt);  grid.sync();
  NS_UPD(Xb, Tt, Xa); grid.sync();
  NS_MUL(V, Xa, Tt);  grid.sync();
  NS_UPD(Xa, Tt, Xb); grid.sync();
  // P7: VinvT (into Xa), dVd, Lw = dt*Vinv@L, Cw = C@V
  {
    Xa[tid*D_ + bid] = Xb[bid*D_ + tid];
    if (tid == bid){ float v = V[bid*D_ + bid]; dVd[bid] = v - bf2f(f2bf(v)); }
    if (tid < UD_){
      float acc = 0.f;
      #pragma unroll 4
      for (int j = 0; j < D_; ++j) acc += Xb[bid*D_ + j] * Lm[j*UD_ + tid];
      Lw[bid*UD_ + tid] = acc * dt[0];
    }
    if (bid < NO_){
      float acc = 0.f;
      #pragma unroll 4
      for (int j = 0; j < D_; ++j) acc += Cmat[bid*D_ + j] * V[j*D_ + tid];
      Cw[bid*D_ + tid] = acc;
    }
  }
  grid.sync();
  // P8: w0 = z0 @ VinvT -> Wchk[0]; Lws pack (bid<32); packA (bid*4+wid < 210)
  {
    const int b0 = bid * 8;
    #pragma unroll
    for (int r = 0; r < 8; ++r) zr[r][tid] = z0[(size_t)(b0+r)*D_ + tid];
    __syncthreads();
    float acc[8] = {0.f,0.f,0.f,0.f,0.f,0.f,0.f,0.f};
    #pragma unroll 4
    for (int j = 0; j < D_; ++j){
      const float vj = Xa[j*D_ + tid];     // VinvT
      #pragma unroll
      for (int r = 0; r < 8; ++r) acc[r] += zr[r][j] * vj;
    }
    #pragma unroll
    for (int r = 0; r < 8; ++r)
      Wchk[(size_t)(b0+r)*D_ + tid] = f2bf(acc[r]);

    if (bid < 32 && tid < 64){
      const int f = bid, l = tid, lm = l & 15, lh = l >> 4;
      const int it = f >> 1, kc2 = f & 1;
      const int ig = it*16 + lm;
      #pragma unroll
      for (int j = 0; j < 8; ++j){
        const int k = 32*kc2 + 4*lh + (j & 3) + 16*(j >> 2);
        Lws[(f*64 + l)*8 + j] = f2bf(k < UD_ ? Lw[ig*UD_ + k] : 0.f);
      }
    }
    {
      const int v = bid*4 + (tid >> 6);
      if (v < 210){
        const int mt = v / 10, kc = v % 10;
        const int l = tid & 63, lm = l & 15, lh = l >> 4;
        const float dts = dt[0];
        #pragma unroll
        for (int j = 0; j < 8; ++j){
          const int k = 32*kc + 4*lh + (j & 3) + 16*(j >> 2);
          float val = 0.f;
          if (mt < 16){
            if (kc < 8) val = V[(mt*16 + lm)*D_ + k];
          } else {
            const int n = (mt - 16)*16 + lm;
            if (kc < 8) val = Cw[n*D_ + k];
            else { const int ku = k - 256; if (ku < UD_) val = dts * Dmat[n*UD_ + ku]; }
          }
          Af[((size_t)(mt*10 + kc)*64 + l)*8 + j] = f2bf(val);
        }
      }
    }
  }
  grid.sync();
  // P9: boundary scan (identical to former k_scan; 256 blocks = 128 bq x 2 ih)
  {
    const int wid = tid >> 6, l = tid & 63;
    const int lm = l & 15, lh = l >> 4;
    const int bq = bid >> 1, ih = bid & 1;
    const int b0 = bq * 16;
    const int row = b0 + lm;
    const int itb = ih*8 + wid*2;

    bf16x8 lwf[4];
    #pragma unroll
    for (int q = 0; q < 2; ++q)
      #pragma unroll
      for (int c = 0; c < 2; ++c)
        lwf[q*2 + c] = *(const bf16x8*)(Lws + ((size_t)(((itb+q)*2 + c)*64 + l))*8);

    float lamr[8], w[8];
    #pragma unroll
    for (int q = 0; q < 2; ++q){
      const int i = (itb+q)*16 + 4*lh;
      const float4 lv = *(const float4*)&lam[i];
      const ushort4 wu = *(const ushort4*)(Wchk + (size_t)row*D_ + i);
      lamr[q*4+0]=lv.x; lamr[q*4+1]=lv.y; lamr[q*4+2]=lv.z; lamr[q*4+3]=lv.w;
      w[q*4+0]=bf2f(wu.x); w[q*4+1]=bf2f(wu.y); w[q*4+2]=bf2f(wu.z); w[q*4+3]=bf2f(wu.w);
    }

    const size_t TS = (size_t)B_ * UD_;
    const float* Urow = U + (size_t)row * UD_;
    float4 Aa, Ab, Ac, Ba, Bb, Bc;
    Aa = *(const float4*)&Urow[4*lh]; Ab = *(const float4*)&Urow[16+4*lh]; Ac = *(const float4*)&Urow[32+4*lh];
    { const float* Up = Urow + TS;
      Ba = *(const float4*)&Up[4*lh]; Bb = *(const float4*)&Up[16+4*lh]; Bc = *(const float4*)&Up[32+4*lh]; }

    #pragma unroll 1
    for (int tt = 0; tt < 64; ++tt){
      const int t0 = 2*tt;
      SCAN_STEP(Aa, Ab, Ac, t0);
      if (t0 + 2 < T_){
        const float* Up = Urow + (size_t)(t0+2)*TS;
        Aa = *(const float4*)&Up[4*lh]; Ab = *(const float4*)&Up[16+4*lh]; Ac = *(const float4*)&Up[32+4*lh];
      }
      SCAN_STEP(Ba, Bb, Bc, t0+1);
      if (t0 + 3 < T_){
        const float* Up = Urow + (size_t)(t0+3)*TS;
        Ba = *(const float4*)&Up[4*lh]; Bb = *(const float4*)&Up[16+4*lh]; Bc = *(const float4*)&Up[32+4*lh];
      }
    }
  }
}

// ---------------- fused replay + output GEMM ----------------
// 1024 blocks = 32 bq x 16 ch x 2 h (h in LOW bit: h0/h1 with same (bq,ch) are
// co-scheduled -> share U + Wchk reads via L2; round-5 had h as top bit = 2 tranches
// apart = 100% refetch). 256 thr = 4 waves.
// Y column split 64/16 (h0: strips 16..19 = cols 0..63 -> 2 full 128B lines/row;
// h1: strip 20 = cols 64..79). Halves the cross-block partial-line RMW on outY
// (320 B rows) vs the 48/32 split.
// LDS h-max: AfZ 64K + Lws 32K + AfY 40K + trbZ 17K + misc 1.5K = 158208 B.
__global__ void __launch_bounds__(256) k_fused(
    const float* __restrict__ U, const ushort_t* __restrict__ Af,
    const ushort_t* __restrict__ Lws, const float* __restrict__ lam,
    const float* __restrict__ dVd, const ushort_t* __restrict__ Wchk,
    float* __restrict__ outZ, float* __restrict__ outY){
  __shared__ __align__(16) ushort_t AfZhL[8*8*512];   // 65536 B  (8 strips x 8 kc)
  __shared__ __align__(16) ushort_t LwsL[32*512];     // 32768 B
  __shared__ __align__(16) ushort_t AfYhL[40*512];    // 40960 B  (h0:4 strips, h1:1)
  __shared__ __align__(16) float    trbZ[4][16][68];  // 17408 B
  __shared__ __align__(16) float    dVdL[128];        // 512 B   (half)
  __shared__ __align__(16) float    lamL[256];        // 1024 B

  const int tid = threadIdx.x;
  const int bid = blockIdx.x;
  const int h  = bid & 1;             // LOW bit: pair h0/h1 share U/Wchk in L2
  const int ch = (bid >> 1) & 15;
  const int bq = bid >> 5;
  const int wid = tid >> 6, l = tid & 63;
  const int lm = l & 15, lh = l >> 4;
  const int col0 = bq*64 + wid*16;
  const int col = col0 + lm;

  // ---- one-time staging ----
  {
    const uint4* gsrc = (const uint4*)Af;
    uint4* dz = (uint4*)AfZhL;
    #pragma unroll
    for (int r = 0; r < 16; ++r){
      const int i = r*256 + tid;            // 0..4095
      const int f = i >> 6, l4 = i & 63;    // f = mi8*8+kc
      const int mi8 = f >> 3, kc = f & 7;
      dz[i] = gsrc[(size_t)((h*8 + mi8)*10 + kc)*64 + l4];
    }
    uint4* dy = (uint4*)AfYhL;
    const int nY = h ? 640 : 2560;
    const int sb = 16 + (h ? 4 : 0);
    #pragma unroll
    for (int r = 0; r < 10; ++r){
      const int i = r*256 + tid;
      if (i < nY){
        const int f = i >> 6, l4 = i & 63;  // f = myl*10 + j
        const int myl = f / 10, j = f % 10;
        dy[i] = gsrc[(size_t)((sb + myl)*10 + j)*64 + l4];
      }
    }
    const uint4* ls = (const uint4*)Lws;
    uint4* ld = (uint4*)LwsL;
    #pragma unroll
    for (int r = 0; r < 8; ++r) ld[r*256 + tid] = ls[r*256 + tid];
    if (tid < 32) ((float4*)dVdL)[tid] = ((const float4*)(dVd + h*128))[tid];
    else if (tid < 96) ((float4*)lamL)[tid-32] = ((const float4*)lam)[tid-32];
  }

  // boundary w (f32 state in regs)
  float w[64];
  #pragma unroll
  for (int kc = 0; kc < 8; ++kc)
    #pragma unroll
    for (int hh = 0; hh < 2; ++hh){
      const int i = 32*kc + 16*hh + 4*lh;
      const ushort4 wu = *(const ushort4*)(Wchk + ((size_t)ch*B_ + col)*D_ + i);
      const int e = 8*kc + 4*hh;
      w[e+0]=bf2f(wu.x); w[e+1]=bf2f(wu.y); w[e+2]=bf2f(wu.z); w[e+3]=bf2f(wu.w);
    }

  // u prefetch for first step
  const size_t TS = (size_t)B_ * UD_;
  const float* Ucol = U + (size_t)col * UD_;
  float4 ua, ub, uc;
  {
    const float* Ut = Ucol + (size_t)(ch*8)*TS;
    ua = *(const float4*)&Ut[4*lh]; ub = *(const float4*)&Ut[16+4*lh]; uc = *(const float4*)&Ut[32+4*lh];
  }

  __syncthreads();   // the only block-wide barrier

#define ZLOOP(HH)                                                               \
  { float* zbase = outZ + ((size_t)t*B_ + col0)*D_ + (HH)*128;                  \
    _Pragma("unroll")                                                           \
    for (int g = 0; g < 2; ++g){                                                \
      _Pragma("unroll")                                                         \
      for (int mi = 0; mi < 4; ++mi){                                           \
        const int mi8 = g*4 + mi;                                               \
        f32x4 acc = {0.f,0.f,0.f,0.f};                                          \
        _Pragma("unroll")                                                       \
        for (int kc = 0; kc < 8; ++kc){                                         \
          const bf16x8 af = *(const bf16x8*)&AfZhL[((mi8*8+kc)*64 + l)*8];      \
          acc = mfma16(af, wfr[kc], acc);                                       \
        }                                                                       \
        const float4 dv = *(const float4*)&dVdL[mi8*16 + 4*lh];                 \
        acc[0] += dv.x * (float)wfr[((HH)*8+mi8)>>1][0 + 4*(mi8&1)];            \
        acc[1] += dv.y * (float)wfr[((HH)*8+mi8)>>1][1 + 4*(mi8&1)];            \
        acc[2] += dv.z * (float)wfr[((HH)*8+mi8)>>1][2 + 4*(mi8&1)];            \
        acc[3] += dv.w * (float)wfr[((HH)*8+mi8)>>1][3 + 4*(mi8&1)];            \
        *(float4*)&trbZ[wid][lm][mi*16 + 4*lh] = make_float4(acc[0],acc[1],acc[2],acc[3]); \
      }                                                                         \
      __builtin_amdgcn_wave_barrier();                                          \
      _Pragma("unroll")                                                         \
      for (int j = 0; j < 4; ++j){                                              \
        const int r_ = j*4 + (l >> 4), c16 = l & 15;                            \
        const float4 v = *(const float4*)&trbZ[wid][r_][4*c16];                 \
        *(float4*)&zbase[(size_t)r_*D_ + g*64 + 4*c16] = v;                     \
      }                                                                         \
      __builtin_amdgcn_wave_barrier();                                          \
    } }

#define YLOOP(COFF, NMY)                                                        \
  { float* yrow = outY + ((size_t)t*B_ + col)*NO_ + (COFF);                     \
    _Pragma("unroll")                                                           \
    for (int my = 0; my < (NMY); ++my){                                         \
      f32x4 acc = {0.f,0.f,0.f,0.f};                                            \
      _Pragma("unroll")                                                         \
      for (int kc = 0; kc < 8; ++kc){                                           \
        const bf16x8 af = *(const bf16x8*)&AfYhL[((my*10+kc)*64 + l)*8];        \
        acc = mfma16(af, wfr[kc], acc);                                         \
      }                                                                         \
      { const bf16x8 af8 = *(const bf16x8*)&AfYhL[((my*10+8)*64 + l)*8];        \
        const bf16x8 af9 = *(const bf16x8*)&AfYhL[((my*10+9)*64 + l)*8];        \
        acc = mfma16(af8, uf0, acc); acc = mfma16(af9, uf1, acc); }             \
      *(float4*)&yrow[my*16 + 4*lh] = make_float4(acc[0],acc[1],acc[2],acc[3]); \
    } }

  #pragma unroll 1
  for (int s = 0; s < 8; ++s){
    const int t = ch*8 + s;
    // build u fragments
    bf16x8 uf0, uf1;
    {
      union { ushort_t us[8]; bf16x8 v; } cv;
      cv.us[0]=f2bf(ua.x); cv.us[1]=f2bf(ua.y); cv.us[2]=f2bf(ua.z); cv.us[3]=f2bf(ua.w);
      cv.us[4]=f2bf(ub.x); cv.us[5]=f2bf(ub.y); cv.us[6]=f2bf(ub.z); cv.us[7]=f2bf(ub.w);
      uf0 = cv.v;
      cv.us[0]=f2bf(uc.x); cv.us[1]=f2bf(uc.y); cv.us[2]=f2bf(uc.z); cv.us[3]=f2bf(uc.w);
      cv.us[4]=0; cv.us[5]=0; cv.us[6]=0; cv.us[7]=0;
      uf1 = cv.v;
    }
    if (s < 7){
      const float* Ut = Ucol + (size_t)(t+1)*TS;
      ua = *(const float4*)&Ut[4*lh]; ub = *(const float4*)&Ut[16+4*lh]; uc = *(const float4*)&Ut[32+4*lh];
    }
    // scan step (lam from LDS)
    #pragma unroll
    for (int it = 0; it < 16; ++it){
      const bf16x8 a0 = *(const bf16x8*)&LwsL[((it*2+0)*64 + l)*8];
      const bf16x8 a1 = *(const bf16x8*)&LwsL[((it*2+1)*64 + l)*8];
      const float4 lv = *(const float4*)&lamL[32*(it>>1) + 16*(it&1) + 4*lh];
      f32x4 acc = {0.f,0.f,0.f,0.f};
      acc = mfma16(a0, uf0, acc);
      acc = mfma16(a1, uf1, acc);
      const int e0 = 8*(it>>1) + 4*(it&1);
      w[e0+0] = lv.x*w[e0+0] + acc[0];
      w[e0+1] = lv.y*w[e0+1] + acc[1];
      w[e0+2] = lv.z*w[e0+2] + acc[2];
      w[e0+3] = lv.w*w[e0+3] + acc[3];
    }
    // pack w fragments
    bf16x8 wfr[8];
    #pragma unroll
    for (int kc = 0; kc < 8; ++kc){
      union { ushort_t us[8]; bf16x8 v; } cv;
      #pragma unroll
      for (int j = 0; j < 8; ++j) cv.us[j] = f2bf(w[8*kc + j]);
      wfr[kc] = cv.v;
    }
    // output GEMMs (h is block-uniform; literal HH keeps wfr indices compile-time)
    if (h == 0){
      ZLOOP(0);
      YLOOP(0, 4);
    } else {
      ZLOOP(1);
      YLOOP(64, 1);
    }
  }
#undef ZLOOP
#undef YLOOP
}

// ---------------- launcher ----------------
extern "C" void kernel_launch(void* const* d_in, const int* in_sizes, int n_in,
                              void* d_out, int out_size, void* d_ws, size_t ws_size,
                              hipStream_t stream){
  const float* z0  = (const float*)d_in[0];
  const float* dt  = (const float*)d_in[2];
  const float* U   = (const float*)d_in[3];
  const float* eig = (const float*)d_in[4];
  const float* V   = (const float*)d_in[5];
  const float* L   = (const float*)d_in[6];
  const float* C   = (const float*)d_in[7];
  const float* Dm  = (const float*)d_in[8];
  float* outZ = (float*)d_out;
  float* outY = outZ + (size_t)T_*B_*D_;

  char* ws = (char*)d_ws;
  float* Xa    = (float*)(ws + 0);        // later reused as VinvT
  float* Xb    = (float*)(ws + 262144);
  float* Tt    = (float*)(ws + 524288);
  float* Lw    = (float*)(ws + 786432);
  float* Cw    = (float*)(ws + 835584);
  float* lam   = (float*)(ws + 917504);
  float* dVd   = (float*)(ws + 918528);
  ushort_t* Af   = (ushort_t*)(ws + 919552);
  ushort_t* Lws  = (ushort_t*)(ws + 1134592);
  ushort_t* Wchk = (ushort_t*)(ws + 1167360);
  if (ws_size < 17944576u) return;

  {
    void* args[] = {
      (void*)&V, (void*)&eig, (void*)&L, (void*)&C, (void*)&Dm, (void*)&dt,
      (void*)&z0, (void*)&U,
      (void*)&Xa, (void*)&Xb, (void*)&Tt, (void*)&Lw, (void*)&Cw,
      (void*)&lam, (void*)&dVd, (void*)&Af, (void*)&Lws, (void*)&Wchk
    };
    hipLaunchCooperativeKernel((const void*)k_prep, dim3(256), dim3(256),
                               args, 0, stream);
  }
  k_fused<<<1024,256,0,stream>>>(U, Af, Lws, lam, dVd, Wchk, outZ, outY);
}

// Round 7
// 411.970 us; speedup vs baseline: 1.3099x; 1.3099x over previous
//
#include <hip/hip_runtime.h>

#define D_   256
#define UD_  48
#define NO_  80
#define T_   128
#define B_   2048

typedef __bf16 bf16x8 __attribute__((ext_vector_type(8)));
typedef float  f32x4  __attribute__((ext_vector_type(4)));
typedef unsigned short ushort_t;

static __device__ __forceinline__ ushort_t f2bf(float f){
  return __builtin_bit_cast(ushort_t, (__bf16)f);
}
static __device__ __forceinline__ float bf2f(ushort_t u){
  union { unsigned int i; float f; } c; c.i = ((unsigned int)u) << 16; return c.f;
}
static __device__ __forceinline__ f32x4 mfma16(bf16x8 a, bf16x8 b, f32x4 c){
  return __builtin_amdgcn_mfma_f32_16x16x32_bf16(a, b, c, 0, 0, 0);
}

// ---------------- Newton-Schulz by columns (no grid sync; round-6 lesson:
// grid.sync ~27us each on 8-XCD MI355X -- launch boundaries are cheaper) ----------

// Iter 1 from X0 = 2I - V, using X0@T = 2T - V@T (no materialized X0 needed).
// Block j owns column j: T[:,j] = V @ X0[:,j];  X1[:,j] = 2*X0[:,j] - 2*T[:,j] + V@T[:,j].
// Also writes X1T row j coalesced. Spare blocks: Cw = C@V (256..335), lam/dVd (336).
__global__ void __launch_bounds__(256) k_ns1(
    const float* __restrict__ V, const float* __restrict__ eig,
    const float* __restrict__ Cmat,
    float* __restrict__ X1, float* __restrict__ XT,
    float* __restrict__ Cw, float* __restrict__ lam, float* __restrict__ dVd){
  __shared__ float xj[256], tl[256];
  const int bid = blockIdx.x, tid = threadIdx.x;
  if (bid < 256){
    const int j = bid;
    xj[tid] = (tid == j ? 2.0f : 0.0f) - V[tid*D_ + j];
    __syncthreads();
    const float4* Vr = (const float4*)(V + tid*D_);
    float a0=0.f,a1=0.f,a2=0.f,a3=0.f;
    #pragma unroll 8
    for (int k = 0; k < 64; ++k){
      const float4 v = Vr[k];
      a0 += v.x*xj[4*k+0]; a1 += v.y*xj[4*k+1];
      a2 += v.z*xj[4*k+2]; a3 += v.w*xj[4*k+3];
    }
    const float t = (a0+a1)+(a2+a3);
    tl[tid] = t;
    __syncthreads();
    float b0=0.f,b1=0.f,b2=0.f,b3=0.f;
    #pragma unroll 8
    for (int k = 0; k < 64; ++k){
      const float4 v = Vr[k];
      b0 += v.x*tl[4*k+0]; b1 += v.y*tl[4*k+1];
      b2 += v.z*tl[4*k+2]; b3 += v.w*tl[4*k+3];
    }
    const float out = 2.f*xj[tid] - 2.f*t + ((b0+b1)+(b2+b3));
    X1[tid*D_ + j] = out;      // normal layout (L2-resident scatter)
    XT[j*D_ + tid] = out;      // transpose row, coalesced
  } else if (bid < 256 + NO_){
    const int n = bid - 256;
    float acc = 0.f;
    #pragma unroll 4
    for (int jj = 0; jj < D_; ++jj) acc += Cmat[n*D_ + jj] * V[jj*D_ + tid];
    Cw[n*D_ + tid] = acc;
  } else {
    lam[tid] = 0.99f / (1.0f + expf(-eig[tid]));
    const float v = V[tid*D_ + tid];
    dVd[tid] = v - bf2f(f2bf(v));
  }
}

// Iters 2,3: Xn[:,j] = 2*Xp[:,j] - Xp @ (V @ Xp[:,j]).
// Reads column j from XT (coalesced), full Xp rows from normal layout.
// XT updated in place (per-row isolation: block j only touches row j).
__global__ void __launch_bounds__(256) k_ns(
    const float* __restrict__ V, const float* __restrict__ Xp,
    float* __restrict__ XT, float* __restrict__ Xn){
  __shared__ float xj[256], tl[256];
  const int j = blockIdx.x, tid = threadIdx.x;
  xj[tid] = XT[j*D_ + tid];
  __syncthreads();
  const float4* Vr = (const float4*)(V + tid*D_);
  float a0=0.f,a1=0.f,a2=0.f,a3=0.f;
  #pragma unroll 8
  for (int k = 0; k < 64; ++k){
    const float4 v = Vr[k];
    a0 += v.x*xj[4*k+0]; a1 += v.y*xj[4*k+1];
    a2 += v.z*xj[4*k+2]; a3 += v.w*xj[4*k+3];
  }
  tl[tid] = (a0+a1)+(a2+a3);
  __syncthreads();
  const float4* Xr = (const float4*)(Xp + tid*D_);
  float b0=0.f,b1=0.f,b2=0.f,b3=0.f;
  #pragma unroll 8
  for (int k = 0; k < 64; ++k){
    const float4 v = Xr[k];
    b0 += v.x*tl[4*k+0]; b1 += v.y*tl[4*k+1];
    b2 += v.z*tl[4*k+2]; b3 += v.w*tl[4*k+3];
  }
  const float out = 2.f*xj[tid] - ((b0+b1)+(b2+b3));
  Xn[tid*D_ + j] = out;
  XT[j*D_ + tid] = out;
}

// ---------------- w0 + Lws + packA (one kernel, 341 blocks) ----------------
// blocks 0..255:   Wchk[0] = z0 @ Vinv^T (8 batch rows/block, coalesced X3T reads)
// blocks 256..287: Lws fragments, Lw[ig,k] = dt * dot(X3 row ig, L[:,k]) on the fly
// blocks 288..340: packA (V / Cw / dt*D fragments); k-map k = 32*kc+4*lh+(j&3)+16*(j>>2)
__global__ void __launch_bounds__(256) k_prep2(
    const float* __restrict__ z0, const float* __restrict__ X3T,
    const float* __restrict__ X3, const float* __restrict__ Lmat,
    const float* __restrict__ V, const float* __restrict__ Cw,
    const float* __restrict__ Dmat, const float* __restrict__ dt,
    ushort_t* __restrict__ Wchk, ushort_t* __restrict__ Lws,
    ushort_t* __restrict__ Af){
  __shared__ float zr[8][256];
  const int bid = blockIdx.x, tid = threadIdx.x;
  if (bid < 256){
    const int b0 = bid * 8;
    #pragma unroll
    for (int r = 0; r < 8; ++r) zr[r][tid] = z0[(size_t)(b0+r)*D_ + tid];
    __syncthreads();
    float acc[8] = {0.f,0.f,0.f,0.f,0.f,0.f,0.f,0.f};
    #pragma unroll 4
    for (int j = 0; j < D_; ++j){
      const float vj = X3T[j*D_ + tid];
      #pragma unroll
      for (int r = 0; r < 8; ++r) acc[r] += zr[r][j] * vj;
    }
    #pragma unroll
    for (int r = 0; r < 8; ++r)
      Wchk[(size_t)(b0+r)*D_ + tid] = f2bf(acc[r]);
  } else if (bid < 288){
    const int f = bid - 256;
    if (tid < 64){
      const int l = tid, lm = l & 15, lh = l >> 4;
      const int it = f >> 1, kc2 = f & 1;
      const int ig = it*16 + lm;
      const float dts = dt[0];
      const float* Xr = X3 + ig*D_;
      float acc[8] = {0.f,0.f,0.f,0.f,0.f,0.f,0.f,0.f};
      #pragma unroll 2
      for (int jj = 0; jj < D_; ++jj){
        const float xv = Xr[jj];
        #pragma unroll
        for (int j = 0; j < 8; ++j){
          const int k = 32*kc2 + 4*lh + (j & 3) + 16*(j >> 2);
          if (k < UD_) acc[j] += xv * Lmat[jj*UD_ + k];
        }
      }
      #pragma unroll
      for (int j = 0; j < 8; ++j){
        const int k = 32*kc2 + 4*lh + (j & 3) + 16*(j >> 2);
        Lws[(f*64 + l)*8 + j] = f2bf(k < UD_ ? acc[j]*dts : 0.f);
      }
    }
  } else {
    const int v = (bid - 288)*4 + (tid >> 6);
    if (v < 210){
      const int mt = v / 10, kc = v % 10;
      const int l = tid & 63, lm = l & 15, lh = l >> 4;
      const float dts = dt[0];
      #pragma unroll
      for (int j = 0; j < 8; ++j){
        const int k = 32*kc + 4*lh + (j & 3) + 16*(j >> 2);
        float val = 0.f;
        if (mt < 16){
          if (kc < 8) val = V[(mt*16 + lm)*D_ + k];
        } else {
          const int n = (mt - 16)*16 + lm;
          if (kc < 8) val = Cw[n*D_ + k];
          else { const int ku = k - 256; if (ku < UD_) val = dts * Dmat[n*UD_ + ku]; }
        }
        Af[((size_t)(mt*10 + kc)*64 + l)*8 + j] = f2bf(val);
      }
    }
  }
}

// ---------------- phase 1: boundary scan (round-5 version, barrier-free) ----------------
#define SCAN_STEP(UA, UB, UC, TT) do {                                          \
  union { ushort_t us[8]; bf16x8 v; } c0, c1;                                   \
  c0.us[0]=f2bf((UA).x); c0.us[1]=f2bf((UA).y); c0.us[2]=f2bf((UA).z); c0.us[3]=f2bf((UA).w); \
  c0.us[4]=f2bf((UB).x); c0.us[5]=f2bf((UB).y); c0.us[6]=f2bf((UB).z); c0.us[7]=f2bf((UB).w); \
  c1.us[0]=f2bf((UC).x); c1.us[1]=f2bf((UC).y); c1.us[2]=f2bf((UC).z); c1.us[3]=f2bf((UC).w); \
  c1.us[4]=0; c1.us[5]=0; c1.us[6]=0; c1.us[7]=0;                               \
  _Pragma("unroll")                                                             \
  for (int q = 0; q < 2; ++q){                                                  \
    f32x4 acc = {0.f,0.f,0.f,0.f};                                              \
    acc = mfma16(lwf[q*2+0], c0.v, acc);                                        \
    acc = mfma16(lwf[q*2+1], c1.v, acc);                                        \
    _Pragma("unroll")                                                           \
    for (int r = 0; r < 4; ++r) w[q*4+r] = lamr[q*4+r]*w[q*4+r] + acc[r];       \
  }                                                                             \
  if ((((TT) & 7) == 7) && ((TT) < T_-1)){                                      \
    const int c2 = ((TT)+1) >> 3;                                               \
    _Pragma("unroll")                                                           \
    for (int q = 0; q < 2; ++q){                                                \
      const int i = (itb+q)*16 + 4*lh;                                          \
      ushort4 o; o.x=f2bf(w[q*4+0]); o.y=f2bf(w[q*4+1]); o.z=f2bf(w[q*4+2]); o.w=f2bf(w[q*4+3]); \
      *(ushort4*)(Wchk + ((size_t)c2*B_ + row)*D_ + i) = o;                     \
    }                                                                           \
  }                                                                             \
} while(0)

__global__ void __launch_bounds__(256) k_scan(const float* __restrict__ U,
    const ushort_t* __restrict__ Lws, const float* __restrict__ lam,
    ushort_t* __restrict__ Wchk){
  const int tid = threadIdx.x;
  const int wid = tid >> 6, l = tid & 63;
  const int lm = l & 15, lh = l >> 4;
  const int bq = blockIdx.x >> 1, ih = blockIdx.x & 1;
  const int b0 = bq * 16;
  const int row = b0 + lm;
  const int itb = ih*8 + wid*2;

  bf16x8 lwf[4];
  #pragma unroll
  for (int q = 0; q < 2; ++q)
    #pragma unroll
    for (int c = 0; c < 2; ++c)
      lwf[q*2 + c] = *(const bf16x8*)(Lws + ((size_t)(((itb+q)*2 + c)*64 + l))*8);

  float lamr[8], w[8];
  #pragma unroll
  for (int q = 0; q < 2; ++q){
    const int i = (itb+q)*16 + 4*lh;
    const float4 lv = *(const float4*)&lam[i];
    const ushort4 wu = *(const ushort4*)(Wchk + (size_t)row*D_ + i);
    lamr[q*4+0]=lv.x; lamr[q*4+1]=lv.y; lamr[q*4+2]=lv.z; lamr[q*4+3]=lv.w;
    w[q*4+0]=bf2f(wu.x); w[q*4+1]=bf2f(wu.y); w[q*4+2]=bf2f(wu.z); w[q*4+3]=bf2f(wu.w);
  }

  const size_t TS = (size_t)B_ * UD_;
  const float* Urow = U + (size_t)row * UD_;
  float4 Aa, Ab, Ac, Ba, Bb, Bc;
  Aa = *(const float4*)&Urow[4*lh]; Ab = *(const float4*)&Urow[16+4*lh]; Ac = *(const float4*)&Urow[32+4*lh];
  { const float* Up = Urow + TS;
    Ba = *(const float4*)&Up[4*lh]; Bb = *(const float4*)&Up[16+4*lh]; Bc = *(const float4*)&Up[32+4*lh]; }

  #pragma unroll 1
  for (int tt = 0; tt < 64; ++tt){
    const int t0 = 2*tt;
    SCAN_STEP(Aa, Ab, Ac, t0);
    if (t0 + 2 < T_){
      const float* Up = Urow + (size_t)(t0+2)*TS;
      Aa = *(const float4*)&Up[4*lh]; Ab = *(const float4*)&Up[16+4*lh]; Ac = *(const float4*)&Up[32+4*lh];
    }
    SCAN_STEP(Ba, Bb, Bc, t0+1);
    if (t0 + 3 < T_){
      const float* Up = Urow + (size_t)(t0+3)*TS;
      Ba = *(const float4*)&Up[4*lh]; Bb = *(const float4*)&Up[16+4*lh]; Bc = *(const float4*)&Up[32+4*lh];
    }
  }
}

// ---------------- fused replay + output GEMM (round-6 version) ----------------
// 1024 blocks = 32 bq x 16 ch x 2 h (h in LOW bit: h0/h1 pair shares U/Wchk via L2).
// Y column split 64/16. LDS h-max 158208 B. 256 thr = 4 waves, VGPR=256.
__global__ void __launch_bounds__(256) k_fused(
    const float* __restrict__ U, const ushort_t* __restrict__ Af,
    const ushort_t* __restrict__ Lws, const float* __restrict__ lam,
    const float* __restrict__ dVd, const ushort_t* __restrict__ Wchk,
    float* __restrict__ outZ, float* __restrict__ outY){
  __shared__ __align__(16) ushort_t AfZhL[8*8*512];   // 65536 B
  __shared__ __align__(16) ushort_t LwsL[32*512];     // 32768 B
  __shared__ __align__(16) ushort_t AfYhL[40*512];    // 40960 B
  __shared__ __align__(16) float    trbZ[4][16][68];  // 17408 B
  __shared__ __align__(16) float    dVdL[128];        // 512 B
  __shared__ __align__(16) float    lamL[256];        // 1024 B

  const int tid = threadIdx.x;
  const int bid = blockIdx.x;
  const int h  = bid & 1;
  const int ch = (bid >> 1) & 15;
  const int bq = bid >> 5;
  const int wid = tid >> 6, l = tid & 63;
  const int lm = l & 15, lh = l >> 4;
  const int col0 = bq*64 + wid*16;
  const int col = col0 + lm;

  // one-time staging
  {
    const uint4* gsrc = (const uint4*)Af;
    uint4* dz = (uint4*)AfZhL;
    #pragma unroll
    for (int r = 0; r < 16; ++r){
      const int i = r*256 + tid;
      const int f = i >> 6, l4 = i & 63;
      const int mi8 = f >> 3, kc = f & 7;
      dz[i] = gsrc[(size_t)((h*8 + mi8)*10 + kc)*64 + l4];
    }
    uint4* dy = (uint4*)AfYhL;
    const int nY = h ? 640 : 2560;
    const int sb = 16 + (h ? 4 : 0);
    #pragma unroll
    for (int r = 0; r < 10; ++r){
      const int i = r*256 + tid;
      if (i < nY){
        const int f = i >> 6, l4 = i & 63;
        const int myl = f / 10, j = f % 10;
        dy[i] = gsrc[(size_t)((sb + myl)*10 + j)*64 + l4];
      }
    }
    const uint4* ls = (const uint4*)Lws;
    uint4* ld = (uint4*)LwsL;
    #pragma unroll
    for (int r = 0; r < 8; ++r) ld[r*256 + tid] = ls[r*256 + tid];
    if (tid < 32) ((float4*)dVdL)[tid] = ((const float4*)(dVd + h*128))[tid];
    else if (tid < 96) ((float4*)lamL)[tid-32] = ((const float4*)lam)[tid-32];
  }

  // boundary w
  float w[64];
  #pragma unroll
  for (int kc = 0; kc < 8; ++kc)
    #pragma unroll
    for (int hh = 0; hh < 2; ++hh){
      const int i = 32*kc + 16*hh + 4*lh;
      const ushort4 wu = *(const ushort4*)(Wchk + ((size_t)ch*B_ + col)*D_ + i);
      const int e = 8*kc + 4*hh;
      w[e+0]=bf2f(wu.x); w[e+1]=bf2f(wu.y); w[e+2]=bf2f(wu.z); w[e+3]=bf2f(wu.w);
    }

  // u prefetch
  const size_t TS = (size_t)B_ * UD_;
  const float* Ucol = U + (size_t)col * UD_;
  float4 ua, ub, uc;
  {
    const float* Ut = Ucol + (size_t)(ch*8)*TS;
    ua = *(const float4*)&Ut[4*lh]; ub = *(const float4*)&Ut[16+4*lh]; uc = *(const float4*)&Ut[32+4*lh];
  }

  __syncthreads();   // the only block-wide barrier

#define ZLOOP(HH)                                                               \
  { float* zbase = outZ + ((size_t)t*B_ + col0)*D_ + (HH)*128;                  \
    _Pragma("unroll")                                                           \
    for (int g = 0; g < 2; ++g){                                                \
      _Pragma("unroll")                                                         \
      for (int mi = 0; mi < 4; ++mi){                                           \
        const int mi8 = g*4 + mi;                                               \
        f32x4 acc = {0.f,0.f,0.f,0.f};                                          \
        _Pragma("unroll")                                                       \
        for (int kc = 0; kc < 8; ++kc){                                         \
          const bf16x8 af = *(const bf16x8*)&AfZhL[((mi8*8+kc)*64 + l)*8];      \
          acc = mfma16(af, wfr[kc], acc);                                       \
        }                                                                       \
        const float4 dv = *(const float4*)&dVdL[mi8*16 + 4*lh];                 \
        acc[0] += dv.x * (float)wfr[((HH)*8+mi8)>>1][0 + 4*(mi8&1)];            \
        acc[1] += dv.y * (float)wfr[((HH)*8+mi8)>>1][1 + 4*(mi8&1)];            \
        acc[2] += dv.z * (float)wfr[((HH)*8+mi8)>>1][2 + 4*(mi8&1)];            \
        acc[3] += dv.w * (float)wfr[((HH)*8+mi8)>>1][3 + 4*(mi8&1)];            \
        *(float4*)&trbZ[wid][lm][mi*16 + 4*lh] = make_float4(acc[0],acc[1],acc[2],acc[3]); \
      }                                                                         \
      __builtin_amdgcn_wave_barrier();                                          \
      _Pragma("unroll")                                                         \
      for (int j = 0; j < 4; ++j){                                              \
        const int r_ = j*4 + (l >> 4), c16 = l & 15;                            \
        const float4 v = *(const float4*)&trbZ[wid][r_][4*c16];                 \
        *(float4*)&zbase[(size_t)r_*D_ + g*64 + 4*c16] = v;                     \
      }                                                                         \
      __builtin_amdgcn_wave_barrier();                                          \
    } }

#define YLOOP(COFF, NMY)                                                        \
  { float* yrow = outY + ((size_t)t*B_ + col)*NO_ + (COFF);                     \
    _Pragma("unroll")                                                           \
    for (int my = 0; my < (NMY); ++my){                                         \
      f32x4 acc = {0.f,0.f,0.f,0.f};                                            \
      _Pragma("unroll")                                                         \
      for (int kc = 0; kc < 8; ++kc){                                           \
        const bf16x8 af = *(const bf16x8*)&AfYhL[((my*10+kc)*64 + l)*8];        \
        acc = mfma16(af, wfr[kc], acc);                                         \
      }                                                                         \
      { const bf16x8 af8 = *(const bf16x8*)&AfYhL[((my*10+8)*64 + l)*8];        \
        const bf16x8 af9 = *(const bf16x8*)&AfYhL[((my*10+9)*64 + l)*8];        \
        acc = mfma16(af8, uf0, acc); acc = mfma16(af9, uf1, acc); }             \
      *(float4*)&yrow[my*16 + 4*lh] = make_float4(acc[0],acc[1],acc[2],acc[3]); \
    } }

  #pragma unroll 1
  for (int s = 0; s < 8; ++s){
    const int t = ch*8 + s;
    bf16x8 uf0, uf1;
    {
      union { ushort_t us[8]; bf16x8 v; } cv;
      cv.us[0]=f2bf(ua.x); cv.us[1]=f2bf(ua.y); cv.us[2]=f2bf(ua.z); cv.us[3]=f2bf(ua.w);
      cv.us[4]=f2bf(ub.x); cv.us[5]=f2bf(ub.y); cv.us[6]=f2bf(ub.z); cv.us[7]=f2bf(ub.w);
      uf0 = cv.v;
      cv.us[0]=f2bf(uc.x); cv.us[1]=f2bf(uc.y); cv.us[2]=f2bf(uc.z); cv.us[3]=f2bf(uc.w);
      cv.us[4]=0; cv.us[5]=0; cv.us[6]=0; cv.us[7]=0;
      uf1 = cv.v;
    }
    if (s < 7){
      const float* Ut = Ucol + (size_t)(t+1)*TS;
      ua = *(const float4*)&Ut[4*lh]; ub = *(const float4*)&Ut[16+4*lh]; uc = *(const float4*)&Ut[32+4*lh];
    }
    #pragma unroll
    for (int it = 0; it < 16; ++it){
      const bf16x8 a0 = *(const bf16x8*)&LwsL[((it*2+0)*64 + l)*8];
      const bf16x8 a1 = *(const bf16x8*)&LwsL[((it*2+1)*64 + l)*8];
      const float4 lv = *(const float4*)&lamL[32*(it>>1) + 16*(it&1) + 4*lh];
      f32x4 acc = {0.f,0.f,0.f,0.f};
      acc = mfma16(a0, uf0, acc);
      acc = mfma16(a1, uf1, acc);
      const int e0 = 8*(it>>1) + 4*(it&1);
      w[e0+0] = lv.x*w[e0+0] + acc[0];
      w[e0+1] = lv.y*w[e0+1] + acc[1];
      w[e0+2] = lv.z*w[e0+2] + acc[2];
      w[e0+3] = lv.w*w[e0+3] + acc[3];
    }
    bf16x8 wfr[8];
    #pragma unroll
    for (int kc = 0; kc < 8; ++kc){
      union { ushort_t us[8]; bf16x8 v; } cv;
      #pragma unroll
      for (int j = 0; j < 8; ++j) cv.us[j] = f2bf(w[8*kc + j]);
      wfr[kc] = cv.v;
    }
    if (h == 0){
      ZLOOP(0);
      YLOOP(0, 4);
    } else {
      ZLOOP(1);
      YLOOP(64, 1);
    }
  }
#undef ZLOOP
#undef YLOOP
}

// ---------------- launcher ----------------
extern "C" void kernel_launch(void* const* d_in, const int* in_sizes, int n_in,
                              void* d_out, int out_size, void* d_ws, size_t ws_size,
                              hipStream_t stream){
  const float* z0  = (const float*)d_in[0];
  const float* dt  = (const float*)d_in[2];
  const float* U   = (const float*)d_in[3];
  const float* eig = (const float*)d_in[4];
  const float* V   = (const float*)d_in[5];
  const float* L   = (const float*)d_in[6];
  const float* C   = (const float*)d_in[7];
  const float* Dm  = (const float*)d_in[8];
  float* outZ = (float*)d_out;
  float* outY = outZ + (size_t)T_*B_*D_;

  char* ws = (char*)d_ws;
  float* Xa    = (float*)(ws + 0);        // X1, then X3 (=Vinv)
  float* Xb    = (float*)(ws + 262144);   // X2
  float* Xt    = (float*)(ws + 524288);   // XT (in-place X1T -> X2T -> X3T)
  float* Cw    = (float*)(ws + 835584);
  float* lam   = (float*)(ws + 917504);
  float* dVd   = (float*)(ws + 918528);
  ushort_t* Af   = (ushort_t*)(ws + 919552);
  ushort_t* Lws  = (ushort_t*)(ws + 1134592);
  ushort_t* Wchk = (ushort_t*)(ws + 1167360);
  if (ws_size < 17944576u) return;

  k_ns1<<<337,256,0,stream>>>(V, eig, C, /*X1=*/Xa, /*XT=*/Xt, Cw, lam, dVd);
  k_ns <<<256,256,0,stream>>>(V, /*Xp=*/Xa, /*XT=*/Xt, /*Xn=*/Xb);   // X2
  k_ns <<<256,256,0,stream>>>(V, /*Xp=*/Xb, /*XT=*/Xt, /*Xn=*/Xa);   // X3 = Vinv
  k_prep2<<<341,256,0,stream>>>(z0, /*X3T=*/Xt, /*X3=*/Xa, L, V, Cw, Dm, dt,
                                Wchk, Lws, Af);
  k_scan<<<256,256,0,stream>>>(U, Lws, lam, Wchk);
  k_fused<<<1024,256,0,stream>>>(U, Af, Lws, lam, dVd, Wchk, outZ, outY);
}

// Round 8
// 298.309 us; speedup vs baseline: 1.8090x; 1.3810x over previous
//
#include <hip/hip_runtime.h>

#define D_   256
#define UD_  48
#define NO_  80
#define T_   128
#define B_   2048

typedef __bf16 bf16x8 __attribute__((ext_vector_type(8)));
typedef float  f32x4  __attribute__((ext_vector_type(4)));
typedef unsigned short ushort_t;

static __device__ __forceinline__ ushort_t f2bf(float f){
  return __builtin_bit_cast(ushort_t, (__bf16)f);
}
static __device__ __forceinline__ float bf2f(ushort_t u){
  union { unsigned int i; float f; } c; c.i = ((unsigned int)u) << 16; return c.f;
}
static __device__ __forceinline__ f32x4 mfma16(bf16x8 a, bf16x8 b, f32x4 c){
  return __builtin_amdgcn_mfma_f32_16x16x32_bf16(a, b, c, 0, 0, 0);
}

// ---------------- prep (round-5 chain verbatim; rounds 6/7 proved the
// "optimized" column-NS + merged prep2 chain is ~144us SLOWER) ----------------

__global__ void k_init(const float* __restrict__ V, const float* __restrict__ eig,
                       float* __restrict__ Xa, float* __restrict__ lam){
  const int i = blockIdx.x, j = threadIdx.x;
  Xa[i*D_ + j] = (i == j ? 2.0f : 0.0f) - V[i*D_ + j];
  if (j == 0) lam[i] = 0.99f / (1.0f + expf(-eig[i]));
}

__global__ void k_mm_mul(const float* __restrict__ A, const float* __restrict__ B,
                         float* __restrict__ Cm){
  const int i = blockIdx.x, j = threadIdx.x;
  const float* Ar = A + i*D_;
  float a0=0.f,a1=0.f,a2=0.f,a3=0.f;
  #pragma unroll 4
  for (int k = 0; k < D_; k += 4){
    a0 += Ar[k+0] * B[(k+0)*D_ + j];
    a1 += Ar[k+1] * B[(k+1)*D_ + j];
    a2 += Ar[k+2] * B[(k+2)*D_ + j];
    a3 += Ar[k+3] * B[(k+3)*D_ + j];
  }
  Cm[i*D_ + j] = (a0+a1)+(a2+a3);
}

__global__ void k_mm_upd(const float* __restrict__ X, const float* __restrict__ Tm,
                         float* __restrict__ Xn){
  const int i = blockIdx.x, j = threadIdx.x;
  const float* Xr = X + i*D_;
  float a0=0.f,a1=0.f,a2=0.f,a3=0.f;
  #pragma unroll 4
  for (int k = 0; k < D_; k += 4){
    a0 += Xr[k+0] * Tm[(k+0)*D_ + j];
    a1 += Xr[k+1] * Tm[(k+1)*D_ + j];
    a2 += Xr[k+2] * Tm[(k+2)*D_ + j];
    a3 += Xr[k+3] * Tm[(k+3)*D_ + j];
  }
  Xn[i*D_ + j] = 2.0f*Xr[j] - ((a0+a1)+(a2+a3));
}

// VinvT = Vinv^T (+dVd); Lw = dt * Vinv @ L; Cw = C @ V
__global__ void k_prep1(const float* __restrict__ Vinv, const float* __restrict__ V,
                        const float* __restrict__ Lm, const float* __restrict__ Cmat,
                        const float* __restrict__ dt,
                        float* __restrict__ VinvT, float* __restrict__ Lw,
                        float* __restrict__ Cw, float* __restrict__ dVd){
  const int bid = blockIdx.x, tid = threadIdx.x;
  if (bid < 256){
    VinvT[tid*D_ + bid] = Vinv[bid*D_ + tid];
    if (tid == bid){ float v = V[bid*D_ + bid]; dVd[bid] = v - bf2f(f2bf(v)); }
  } else if (bid < 512){
    const int i = bid - 256;
    if (tid < UD_){
      float acc = 0.f;
      #pragma unroll 4
      for (int j = 0; j < D_; ++j) acc += Vinv[i*D_ + j] * Lm[j*UD_ + tid];
      Lw[i*UD_ + tid] = acc * dt[0];
    }
  } else {
    const int n = bid - 512;
    float acc = 0.f;
    #pragma unroll 4
    for (int j = 0; j < D_; ++j) acc += Cmat[n*D_ + j] * V[j*D_ + tid];
    Cw[n*D_ + tid] = acc;
  }
}

// w0 = z0 @ VinvT -> Wchk[0] (bf16), 8 rows/block; pack Lws A-fragments.
// k-map (bijective, A/B consistent): k = 32*kc + 4*lh + (j&3) + 16*(j>>2)
__global__ void k_prep2(const float* __restrict__ z0, const float* __restrict__ VinvT,
                        const float* __restrict__ Lw,
                        ushort_t* __restrict__ Wchk, ushort_t* __restrict__ Lws){
  __shared__ float zr[8][256];
  const int bid = blockIdx.x, tid = threadIdx.x;
  if (bid < 256){
    const int b0 = bid * 8;
    #pragma unroll
    for (int r = 0; r < 8; ++r) zr[r][tid] = z0[(size_t)(b0+r)*D_ + tid];
    __syncthreads();
    float acc[8] = {0.f,0.f,0.f,0.f,0.f,0.f,0.f,0.f};
    #pragma unroll 4
    for (int j = 0; j < D_; ++j){
      const float vj = VinvT[j*D_ + tid];
      #pragma unroll
      for (int r = 0; r < 8; ++r) acc[r] += zr[r][j] * vj;
    }
    #pragma unroll
    for (int r = 0; r < 8; ++r)
      Wchk[(size_t)(b0+r)*D_ + tid] = f2bf(acc[r]);
    return;
  }
  const int f = bid - 256;             // 0..31
  if (tid >= 64) return;
  const int l = tid, lm = l & 15, lh = l >> 4;
  const int it = f >> 1, kc2 = f & 1;
  const int ig = it*16 + lm;
  #pragma unroll
  for (int j = 0; j < 8; ++j){
    const int k = 32*kc2 + 4*lh + (j & 3) + 16*(j >> 2);
    Lws[(f*64 + l)*8 + j] = f2bf(k < UD_ ? Lw[ig*UD_ + k] : 0.f);
  }
}

// Pack augmented A fragments: rows 0..255 = V (Z), 256..335 = [Cw | dt*D] (Y). K=320.
__global__ void k_packA(const float* __restrict__ V, const float* __restrict__ Cw,
                        const float* __restrict__ Dmat, const float* __restrict__ dt,
                        ushort_t* __restrict__ Af){
  const int mt = blockIdx.x / 10, kc = blockIdx.x % 10;
  const int l = threadIdx.x, lm = l & 15, lh = l >> 4;
  const float dts = dt[0];
  #pragma unroll
  for (int j = 0; j < 8; ++j){
    const int k = 32*kc + 4*lh + (j & 3) + 16*(j >> 2);
    float val = 0.f;
    if (mt < 16){
      if (kc < 8) val = V[(mt*16 + lm)*D_ + k];
    } else {
      const int n = (mt - 16)*16 + lm;
      if (kc < 8) val = Cw[n*D_ + k];
      else { const int ku = k - 256; if (ku < UD_) val = dts * Dmat[n*UD_ + ku]; }
    }
    Af[((size_t)(mt*10 + kc)*64 + l)*8 + j] = f2bf(val);
  }
}

// ---------------- phase 1: boundary scan (round-5, barrier-free) ----------------
#define SCAN_STEP(UA, UB, UC, TT) do {                                          \
  union { ushort_t us[8]; bf16x8 v; } c0, c1;                                   \
  c0.us[0]=f2bf((UA).x); c0.us[1]=f2bf((UA).y); c0.us[2]=f2bf((UA).z); c0.us[3]=f2bf((UA).w); \
  c0.us[4]=f2bf((UB).x); c0.us[5]=f2bf((UB).y); c0.us[6]=f2bf((UB).z); c0.us[7]=f2bf((UB).w); \
  c1.us[0]=f2bf((UC).x); c1.us[1]=f2bf((UC).y); c1.us[2]=f2bf((UC).z); c1.us[3]=f2bf((UC).w); \
  c1.us[4]=0; c1.us[5]=0; c1.us[6]=0; c1.us[7]=0;                               \
  _Pragma("unroll")                                                             \
  for (int q = 0; q < 2; ++q){                                                  \
    f32x4 acc = {0.f,0.f,0.f,0.f};                                              \
    acc = mfma16(lwf[q*2+0], c0.v, acc);                                        \
    acc = mfma16(lwf[q*2+1], c1.v, acc);                                        \
    _Pragma("unroll")                                                           \
    for (int r = 0; r < 4; ++r) w[q*4+r] = lamr[q*4+r]*w[q*4+r] + acc[r];       \
  }                                                                             \
  if ((((TT) & 7) == 7) && ((TT) < T_-1)){                                      \
    const int c2 = ((TT)+1) >> 3;                                               \
    _Pragma("unroll")                                                           \
    for (int q = 0; q < 2; ++q){                                                \
      const int i = (itb+q)*16 + 4*lh;                                          \
      ushort4 o; o.x=f2bf(w[q*4+0]); o.y=f2bf(w[q*4+1]); o.z=f2bf(w[q*4+2]); o.w=f2bf(w[q*4+3]); \
      *(ushort4*)(Wchk + ((size_t)c2*B_ + row)*D_ + i) = o;                     \
    }                                                                           \
  }                                                                             \
} while(0)

__global__ void __launch_bounds__(256) k_scan(const float* __restrict__ U,
    const ushort_t* __restrict__ Lws, const float* __restrict__ lam,
    ushort_t* __restrict__ Wchk){
  const int tid = threadIdx.x;
  const int wid = tid >> 6, l = tid & 63;
  const int lm = l & 15, lh = l >> 4;
  const int bq = blockIdx.x >> 1, ih = blockIdx.x & 1;
  const int b0 = bq * 16;
  const int row = b0 + lm;
  const int itb = ih*8 + wid*2;

  bf16x8 lwf[4];
  #pragma unroll
  for (int q = 0; q < 2; ++q)
    #pragma unroll
    for (int c = 0; c < 2; ++c)
      lwf[q*2 + c] = *(const bf16x8*)(Lws + ((size_t)(((itb+q)*2 + c)*64 + l))*8);

  float lamr[8], w[8];
  #pragma unroll
  for (int q = 0; q < 2; ++q){
    const int i = (itb+q)*16 + 4*lh;
    const float4 lv = *(const float4*)&lam[i];
    const ushort4 wu = *(const ushort4*)(Wchk + (size_t)row*D_ + i);
    lamr[q*4+0]=lv.x; lamr[q*4+1]=lv.y; lamr[q*4+2]=lv.z; lamr[q*4+3]=lv.w;
    w[q*4+0]=bf2f(wu.x); w[q*4+1]=bf2f(wu.y); w[q*4+2]=bf2f(wu.z); w[q*4+3]=bf2f(wu.w);
  }

  const size_t TS = (size_t)B_ * UD_;
  const float* Urow = U + (size_t)row * UD_;
  float4 Aa, Ab, Ac, Ba, Bb, Bc;
  Aa = *(const float4*)&Urow[4*lh]; Ab = *(const float4*)&Urow[16+4*lh]; Ac = *(const float4*)&Urow[32+4*lh];
  { const float* Up = Urow + TS;
    Ba = *(const float4*)&Up[4*lh]; Bb = *(const float4*)&Up[16+4*lh]; Bc = *(const float4*)&Up[32+4*lh]; }

  #pragma unroll 1
  for (int tt = 0; tt < 64; ++tt){
    const int t0 = 2*tt;
    SCAN_STEP(Aa, Ab, Ac, t0);
    if (t0 + 2 < T_){
      const float* Up = Urow + (size_t)(t0+2)*TS;
      Aa = *(const float4*)&Up[4*lh]; Ab = *(const float4*)&Up[16+4*lh]; Ac = *(const float4*)&Up[32+4*lh];
    }
    SCAN_STEP(Ba, Bb, Bc, t0+1);
    if (t0 + 3 < T_){
      const float* Up = Urow + (size_t)(t0+3)*TS;
      Ba = *(const float4*)&Up[4*lh]; Bb = *(const float4*)&Up[16+4*lh]; Bc = *(const float4*)&Up[32+4*lh];
    }
  }
}

// ---------------- fused replay + output GEMM (STEP-PAIRED) ----------------
// LDS-read-bound diagnosis: old version issued ~168 ds_read_b128/step/wave (12 cyc
// each > MFMA 5 cyc) -> ~108us of pure LDS throughput. Step-pairing reads every
// A-fragment ONCE per 2 steps and feeds 2 MFMAs (wfrA/wfrB, ufA/ufB): 336 -> 136
// reads per pair. 1024 blocks = 32 bq x 16 ch x 2 h (h low bit); 256 thr = 4 waves.
__global__ void __launch_bounds__(256) k_fused(
    const float* __restrict__ U, const ushort_t* __restrict__ Af,
    const ushort_t* __restrict__ Lws, const float* __restrict__ lam,
    const float* __restrict__ dVd, const ushort_t* __restrict__ Wchk,
    float* __restrict__ outZ, float* __restrict__ outY){
  __shared__ __align__(16) ushort_t AfZhL[8*8*512];   // 65536 B
  __shared__ __align__(16) ushort_t LwsL[32*512];     // 32768 B
  __shared__ __align__(16) ushort_t AfYhL[40*512];    // 40960 B
  __shared__ __align__(16) float    trbZ[4][16][68];  // 17408 B
  __shared__ __align__(16) float    dVdL[128];        // 512 B
  __shared__ __align__(16) float    lamL[256];        // 1024 B

  const int tid = threadIdx.x;
  const int bid = blockIdx.x;
  const int h  = bid & 1;
  const int ch = (bid >> 1) & 15;
  const int bq = bid >> 5;
  const int wid = tid >> 6, l = tid & 63;
  const int lm = l & 15, lh = l >> 4;
  const int col0 = bq*64 + wid*16;
  const int col = col0 + lm;

  // one-time staging
  {
    const uint4* gsrc = (const uint4*)Af;
    uint4* dz = (uint4*)AfZhL;
    #pragma unroll
    for (int r = 0; r < 16; ++r){
      const int i = r*256 + tid;
      const int f = i >> 6, l4 = i & 63;
      const int mi8 = f >> 3, kc = f & 7;
      dz[i] = gsrc[(size_t)((h*8 + mi8)*10 + kc)*64 + l4];
    }
    uint4* dy = (uint4*)AfYhL;
    const int nY = h ? 640 : 2560;
    const int sb = 16 + (h ? 4 : 0);
    #pragma unroll
    for (int r = 0; r < 10; ++r){
      const int i = r*256 + tid;
      if (i < nY){
        const int f = i >> 6, l4 = i & 63;
        const int myl = f / 10, j = f % 10;
        dy[i] = gsrc[(size_t)((sb + myl)*10 + j)*64 + l4];
      }
    }
    const uint4* ls = (const uint4*)Lws;
    uint4* ld = (uint4*)LwsL;
    #pragma unroll
    for (int r = 0; r < 8; ++r) ld[r*256 + tid] = ls[r*256 + tid];
    if (tid < 32) ((float4*)dVdL)[tid] = ((const float4*)(dVd + h*128))[tid];
    else if (tid < 96) ((float4*)lamL)[tid-32] = ((const float4*)lam)[tid-32];
  }

  // boundary w
  float w[64];
  #pragma unroll
  for (int kc = 0; kc < 8; ++kc)
    #pragma unroll
    for (int hh = 0; hh < 2; ++hh){
      const int i = 32*kc + 16*hh + 4*lh;
      const ushort4 wu = *(const ushort4*)(Wchk + ((size_t)ch*B_ + col)*D_ + i);
      const int e = 8*kc + 4*hh;
      w[e+0]=bf2f(wu.x); w[e+1]=bf2f(wu.y); w[e+2]=bf2f(wu.z); w[e+3]=bf2f(wu.w);
    }

  // u prefetch for pair 0 (steps t0, t0+1)
  const size_t TS = (size_t)B_ * UD_;
  const float* Ucol = U + (size_t)col * UD_;
  float4 uaA, ubA, ucA, uaB, ubB, ucB;
  {
    const float* Ut = Ucol + (size_t)(ch*8)*TS;
    uaA = *(const float4*)&Ut[4*lh]; ubA = *(const float4*)&Ut[16+4*lh]; ucA = *(const float4*)&Ut[32+4*lh];
    const float* Ut1 = Ut + TS;
    uaB = *(const float4*)&Ut1[4*lh]; ubB = *(const float4*)&Ut1[16+4*lh]; ucB = *(const float4*)&Ut1[32+4*lh];
  }

  __syncthreads();   // the only block-wide barrier

#define ZLOOP(HH)                                                               \
  { float* zA = outZ + ((size_t)t*B_ + col0)*D_ + (HH)*128;                     \
    float* zB = zA + (size_t)B_*D_;                                             \
    _Pragma("unroll")                                                           \
    for (int g = 0; g < 4; ++g){                                                \
      _Pragma("unroll")                                                         \
      for (int mi = 0; mi < 2; ++mi){                                           \
        const int mi8 = g*2 + mi;                                               \
        f32x4 aA = {0.f,0.f,0.f,0.f}, aB = {0.f,0.f,0.f,0.f};                   \
        _Pragma("unroll")                                                       \
        for (int kc = 0; kc < 8; ++kc){                                         \
          const bf16x8 af = *(const bf16x8*)&AfZhL[((mi8*8+kc)*64 + l)*8];      \
          aA = mfma16(af, wfrA[kc], aA);                                        \
          aB = mfma16(af, wfrB[kc], aB);                                        \
        }                                                                       \
        const float4 dv = *(const float4*)&dVdL[mi8*16 + 4*lh];                 \
        _Pragma("unroll")                                                       \
        for (int r = 0; r < 4; ++r){                                            \
          aA[r] += ((const float*)&dv)[r] * (float)wfrA[(HH)*4+(mi8>>1)][r + 4*(mi8&1)]; \
          aB[r] += ((const float*)&dv)[r] * (float)wfrB[(HH)*4+(mi8>>1)][r + 4*(mi8&1)]; \
        }                                                                       \
        *(float4*)&trbZ[wid][lm][mi*16 + 4*lh] = make_float4(aA[0],aA[1],aA[2],aA[3]); \
        *(float4*)&trbZ[wid][lm][32 + mi*16 + 4*lh] = make_float4(aB[0],aB[1],aB[2],aB[3]); \
      }                                                                         \
      __builtin_amdgcn_wave_barrier();                                          \
      _Pragma("unroll")                                                         \
      for (int j = 0; j < 4; ++j){                                              \
        const int stp = j >> 1, jr = (j & 1)*8;                                 \
        const int r_ = jr + (l >> 3), c8 = l & 7;                               \
        const float4 v = *(const float4*)&trbZ[wid][r_][stp*32 + 4*c8];         \
        float* dst = stp ? zB : zA;                                             \
        *(float4*)&dst[(size_t)r_*D_ + g*32 + 4*c8] = v;                        \
      }                                                                         \
      __builtin_amdgcn_wave_barrier();                                          \
    } }

#define YLOOP(COFF, NMY)                                                        \
  { float* yA = outY + ((size_t)t*B_ + col)*NO_ + (COFF);                       \
    float* yB = yA + (size_t)B_*NO_;                                            \
    _Pragma("unroll")                                                           \
    for (int my = 0; my < (NMY); ++my){                                         \
      f32x4 aA = {0.f,0.f,0.f,0.f}, aB = {0.f,0.f,0.f,0.f};                     \
      _Pragma("unroll")                                                         \
      for (int kc = 0; kc < 8; ++kc){                                           \
        const bf16x8 af = *(const bf16x8*)&AfYhL[((my*10+kc)*64 + l)*8];        \
        aA = mfma16(af, wfrA[kc], aA);                                          \
        aB = mfma16(af, wfrB[kc], aB);                                          \
      }                                                                         \
      { const bf16x8 af8 = *(const bf16x8*)&AfYhL[((my*10+8)*64 + l)*8];        \
        const bf16x8 af9 = *(const bf16x8*)&AfYhL[((my*10+9)*64 + l)*8];        \
        aA = mfma16(af8, ufA0, aA); aA = mfma16(af9, ufA1, aA);                 \
        aB = mfma16(af8, ufB0, aB); aB = mfma16(af9, ufB1, aB); }               \
      *(float4*)&yA[my*16 + 4*lh] = make_float4(aA[0],aA[1],aA[2],aA[3]);       \
      *(float4*)&yB[my*16 + 4*lh] = make_float4(aB[0],aB[1],aB[2],aB[3]);       \
    } }

  #pragma unroll 1
  for (int p = 0; p < 4; ++p){
    const int t = ch*8 + 2*p;
    // build u fragments for both steps of the pair
    bf16x8 ufA0, ufA1, ufB0, ufB1;
    {
      union { ushort_t us[8]; bf16x8 v; } cv;
      cv.us[0]=f2bf(uaA.x); cv.us[1]=f2bf(uaA.y); cv.us[2]=f2bf(uaA.z); cv.us[3]=f2bf(uaA.w);
      cv.us[4]=f2bf(ubA.x); cv.us[5]=f2bf(ubA.y); cv.us[6]=f2bf(ubA.z); cv.us[7]=f2bf(ubA.w);
      ufA0 = cv.v;
      cv.us[0]=f2bf(ucA.x); cv.us[1]=f2bf(ucA.y); cv.us[2]=f2bf(ucA.z); cv.us[3]=f2bf(ucA.w);
      cv.us[4]=0; cv.us[5]=0; cv.us[6]=0; cv.us[7]=0;
      ufA1 = cv.v;
      cv.us[0]=f2bf(uaB.x); cv.us[1]=f2bf(uaB.y); cv.us[2]=f2bf(uaB.z); cv.us[3]=f2bf(uaB.w);
      cv.us[4]=f2bf(ubB.x); cv.us[5]=f2bf(ubB.y); cv.us[6]=f2bf(ubB.z); cv.us[7]=f2bf(ubB.w);
      ufB0 = cv.v;
      cv.us[0]=f2bf(ucB.x); cv.us[1]=f2bf(ucB.y); cv.us[2]=f2bf(ucB.z); cv.us[3]=f2bf(ucB.w);
      cv.us[4]=0; cv.us[5]=0; cv.us[6]=0; cv.us[7]=0;
      ufB1 = cv.v;
    }
    // prefetch next pair's u (arrives during Z/Y passes)
    if (p < 3){
      const float* Ut = Ucol + (size_t)(t+2)*TS;
      uaA = *(const float4*)&Ut[4*lh]; ubA = *(const float4*)&Ut[16+4*lh]; ucA = *(const float4*)&Ut[32+4*lh];
      const float* Ut1 = Ut + TS;
      uaB = *(const float4*)&Ut1[4*lh]; ubB = *(const float4*)&Ut1[16+4*lh]; ucB = *(const float4*)&Ut1[32+4*lh];
    }
    // interleaved scan: each LwsL fragment read once, used for both steps
    bf16x8 wfrA[8], wfrB[8];
    {
      union u8 { ushort_t us[8]; bf16x8 v; } cvA[8];
      #pragma unroll
      for (int it = 0; it < 16; ++it){
        const bf16x8 a0 = *(const bf16x8*)&LwsL[((it*2+0)*64 + l)*8];
        const bf16x8 a1 = *(const bf16x8*)&LwsL[((it*2+1)*64 + l)*8];
        const float4 lv = *(const float4*)&lamL[32*(it>>1) + 16*(it&1) + 4*lh];
        f32x4 pA = {0.f,0.f,0.f,0.f};
        pA = mfma16(a0, ufA0, pA);
        pA = mfma16(a1, ufA1, pA);
        f32x4 pB = {0.f,0.f,0.f,0.f};
        pB = mfma16(a0, ufB0, pB);
        pB = mfma16(a1, ufB1, pB);
        const int e0 = 8*(it>>1) + 4*(it&1);
        const float wa0 = lv.x*w[e0+0] + pA[0];
        const float wa1 = lv.y*w[e0+1] + pA[1];
        const float wa2 = lv.z*w[e0+2] + pA[2];
        const float wa3 = lv.w*w[e0+3] + pA[3];
        w[e0+0] = lv.x*wa0 + pB[0];
        w[e0+1] = lv.y*wa1 + pB[1];
        w[e0+2] = lv.z*wa2 + pB[2];
        w[e0+3] = lv.w*wa3 + pB[3];
        cvA[it>>1].us[4*(it&1)+0] = f2bf(wa0);
        cvA[it>>1].us[4*(it&1)+1] = f2bf(wa1);
        cvA[it>>1].us[4*(it&1)+2] = f2bf(wa2);
        cvA[it>>1].us[4*(it&1)+3] = f2bf(wa3);
      }
      #pragma unroll
      for (int kc = 0; kc < 8; ++kc){
        wfrA[kc] = cvA[kc].v;
        union u8 cv;
        #pragma unroll
        for (int j = 0; j < 8; ++j) cv.us[j] = f2bf(w[8*kc + j]);
        wfrB[kc] = cv.v;
      }
    }
    // output GEMMs for both steps (A-frags read once)
    if (h == 0){
      ZLOOP(0);
      YLOOP(0, 4);
    } else {
      ZLOOP(1);
      YLOOP(64, 1);
    }
  }
#undef ZLOOP
#undef YLOOP
}

// ---------------- launcher ----------------
extern "C" void kernel_launch(void* const* d_in, const int* in_sizes, int n_in,
                              void* d_out, int out_size, void* d_ws, size_t ws_size,
                              hipStream_t stream){
  const float* z0  = (const float*)d_in[0];
  const float* dt  = (const float*)d_in[2];
  const float* U   = (const float*)d_in[3];
  const float* eig = (const float*)d_in[4];
  const float* V   = (const float*)d_in[5];
  const float* L   = (const float*)d_in[6];
  const float* C   = (const float*)d_in[7];
  const float* Dm  = (const float*)d_in[8];
  float* outZ = (float*)d_out;
  float* outY = outZ + (size_t)T_*B_*D_;

  char* ws = (char*)d_ws;
  float* Xa    = (float*)(ws + 0);        // later reused as VinvT
  float* Xb    = (float*)(ws + 262144);
  float* Tt    = (float*)(ws + 524288);
  float* Lw    = (float*)(ws + 786432);
  float* Cw    = (float*)(ws + 835584);
  float* lam   = (float*)(ws + 917504);
  float* dVd   = (float*)(ws + 918528);
  ushort_t* Af   = (ushort_t*)(ws + 919552);
  ushort_t* Lws  = (ushort_t*)(ws + 1134592);
  ushort_t* Wchk = (ushort_t*)(ws + 1167360);
  if (ws_size < 17944576u) return;

  k_init<<<256,256,0,stream>>>(V, eig, Xa, lam);
  // Newton-Schulz, 3 iters from X0 = 2I - V  -> Vinv = Xb
  k_mm_mul<<<256,256,0,stream>>>(V, Xa, Tt);
  k_mm_upd<<<256,256,0,stream>>>(Xa, Tt, Xb);
  k_mm_mul<<<256,256,0,stream>>>(V, Xb, Tt);
  k_mm_upd<<<256,256,0,stream>>>(Xb, Tt, Xa);
  k_mm_mul<<<256,256,0,stream>>>(V, Xa, Tt);
  k_mm_upd<<<256,256,0,stream>>>(Xa, Tt, Xb);
  k_prep1<<<592,256,0,stream>>>(Xb, V, L, C, dt, /*VinvT=*/Xa, Lw, Cw, dVd);
  k_prep2<<<288,256,0,stream>>>(z0, /*VinvT=*/Xa, Lw, Wchk, Lws);
  k_packA<<<210,64,0,stream>>>(V, Cw, Dm, dt, Af);
  k_scan<<<256,256,0,stream>>>(U, Lws, lam, Wchk);
  k_fused<<<1024,256,0,stream>>>(U, Af, Lws, lam, dVd, Wchk, outZ, outY);
}

// Round 9
// 286.748 us; speedup vs baseline: 1.8819x; 1.0403x over previous
//
#include <hip/hip_runtime.h>

#define D_   256
#define UD_  48
#define NO_  80
#define T_   128
#define B_   2048

typedef __bf16 bf16x8 __attribute__((ext_vector_type(8)));
typedef float  f32x4  __attribute__((ext_vector_type(4)));
typedef unsigned short ushort_t;

static __device__ __forceinline__ ushort_t f2bf(float f){
  return __builtin_bit_cast(ushort_t, (__bf16)f);
}
static __device__ __forceinline__ float bf2f(ushort_t u){
  union { unsigned int i; float f; } c; c.i = ((unsigned int)u) << 16; return c.f;
}
static __device__ __forceinline__ unsigned pack2bf(float a, float b){
  return ((unsigned)f2bf(b) << 16) | (unsigned)f2bf(a);
}
static __device__ __forceinline__ f32x4 mfma16(bf16x8 a, bf16x8 b, f32x4 c){
  return __builtin_amdgcn_mfma_f32_16x16x32_bf16(a, b, c, 0, 0, 0);
}
#define BFV(u) __builtin_bit_cast(bf16x8, (u))

// ---------------- prep (round-5 chain verbatim) ----------------

__global__ void k_init(const float* __restrict__ V, const float* __restrict__ eig,
                       float* __restrict__ Xa, float* __restrict__ lam){
  const int i = blockIdx.x, j = threadIdx.x;
  Xa[i*D_ + j] = (i == j ? 2.0f : 0.0f) - V[i*D_ + j];
  if (j == 0) lam[i] = 0.99f / (1.0f + expf(-eig[i]));
}

__global__ void k_mm_mul(const float* __restrict__ A, const float* __restrict__ B,
                         float* __restrict__ Cm){
  const int i = blockIdx.x, j = threadIdx.x;
  const float* Ar = A + i*D_;
  float a0=0.f,a1=0.f,a2=0.f,a3=0.f;
  #pragma unroll 4
  for (int k = 0; k < D_; k += 4){
    a0 += Ar[k+0] * B[(k+0)*D_ + j];
    a1 += Ar[k+1] * B[(k+1)*D_ + j];
    a2 += Ar[k+2] * B[(k+2)*D_ + j];
    a3 += Ar[k+3] * B[(k+3)*D_ + j];
  }
  Cm[i*D_ + j] = (a0+a1)+(a2+a3);
}

__global__ void k_mm_upd(const float* __restrict__ X, const float* __restrict__ Tm,
                         float* __restrict__ Xn){
  const int i = blockIdx.x, j = threadIdx.x;
  const float* Xr = X + i*D_;
  float a0=0.f,a1=0.f,a2=0.f,a3=0.f;
  #pragma unroll 4
  for (int k = 0; k < D_; k += 4){
    a0 += Xr[k+0] * Tm[(k+0)*D_ + j];
    a1 += Xr[k+1] * Tm[(k+1)*D_ + j];
    a2 += Xr[k+2] * Tm[(k+2)*D_ + j];
    a3 += Xr[k+3] * Tm[(k+3)*D_ + j];
  }
  Xn[i*D_ + j] = 2.0f*Xr[j] - ((a0+a1)+(a2+a3));
}

// VinvT = Vinv^T (+dVd); Lw = dt * Vinv @ L; Cw = C @ V
__global__ void k_prep1(const float* __restrict__ Vinv, const float* __restrict__ V,
                        const float* __restrict__ Lm, const float* __restrict__ Cmat,
                        const float* __restrict__ dt,
                        float* __restrict__ VinvT, float* __restrict__ Lw,
                        float* __restrict__ Cw, float* __restrict__ dVd){
  const int bid = blockIdx.x, tid = threadIdx.x;
  if (bid < 256){
    VinvT[tid*D_ + bid] = Vinv[bid*D_ + tid];
    if (tid == bid){ float v = V[bid*D_ + bid]; dVd[bid] = v - bf2f(f2bf(v)); }
  } else if (bid < 512){
    const int i = bid - 256;
    if (tid < UD_){
      float acc = 0.f;
      #pragma unroll 4
      for (int j = 0; j < D_; ++j) acc += Vinv[i*D_ + j] * Lm[j*UD_ + tid];
      Lw[i*UD_ + tid] = acc * dt[0];
    }
  } else {
    const int n = bid - 512;
    float acc = 0.f;
    #pragma unroll 4
    for (int j = 0; j < D_; ++j) acc += Cmat[n*D_ + j] * V[j*D_ + tid];
    Cw[n*D_ + tid] = acc;
  }
}

// w0 = z0 @ VinvT -> Wchk[0] (bf16), 8 rows/block; pack Lws A-fragments.
__global__ void k_prep2(const float* __restrict__ z0, const float* __restrict__ VinvT,
                        const float* __restrict__ Lw,
                        ushort_t* __restrict__ Wchk, ushort_t* __restrict__ Lws){
  __shared__ float zr[8][256];
  const int bid = blockIdx.x, tid = threadIdx.x;
  if (bid < 256){
    const int b0 = bid * 8;
    #pragma unroll
    for (int r = 0; r < 8; ++r) zr[r][tid] = z0[(size_t)(b0+r)*D_ + tid];
    __syncthreads();
    float acc[8] = {0.f,0.f,0.f,0.f,0.f,0.f,0.f,0.f};
    #pragma unroll 4
    for (int j = 0; j < D_; ++j){
      const float vj = VinvT[j*D_ + tid];
      #pragma unroll
      for (int r = 0; r < 8; ++r) acc[r] += zr[r][j] * vj;
    }
    #pragma unroll
    for (int r = 0; r < 8; ++r)
      Wchk[(size_t)(b0+r)*D_ + tid] = f2bf(acc[r]);
    return;
  }
  const int f = bid - 256;             // 0..31
  if (tid >= 64) return;
  const int l = tid, lm = l & 15, lh = l >> 4;
  const int it = f >> 1, kc2 = f & 1;
  const int ig = it*16 + lm;
  #pragma unroll
  for (int j = 0; j < 8; ++j){
    const int k = 32*kc2 + 4*lh + (j & 3) + 16*(j >> 2);
    Lws[(f*64 + l)*8 + j] = f2bf(k < UD_ ? Lw[ig*UD_ + k] : 0.f);
  }
}

// Pack augmented A fragments: rows 0..255 = V (Z), 256..335 = [Cw | dt*D] (Y). K=320.
__global__ void k_packA(const float* __restrict__ V, const float* __restrict__ Cw,
                        const float* __restrict__ Dmat, const float* __restrict__ dt,
                        ushort_t* __restrict__ Af){
  const int mt = blockIdx.x / 10, kc = blockIdx.x % 10;
  const int l = threadIdx.x, lm = l & 15, lh = l >> 4;
  const float dts = dt[0];
  #pragma unroll
  for (int j = 0; j < 8; ++j){
    const int k = 32*kc + 4*lh + (j & 3) + 16*(j >> 2);
    float val = 0.f;
    if (mt < 16){
      if (kc < 8) val = V[(mt*16 + lm)*D_ + k];
    } else {
      const int n = (mt - 16)*16 + lm;
      if (kc < 8) val = Cw[n*D_ + k];
      else { const int ku = k - 256; if (ku < UD_) val = dts * Dmat[n*UD_ + ku]; }
    }
    Af[((size_t)(mt*10 + kc)*64 + l)*8 + j] = f2bf(val);
  }
}

// ---------------- phase 1: boundary scan (round-5, barrier-free) ----------------
#define SCAN_STEP(UA, UB, UC, TT) do {                                          \
  union { ushort_t us[8]; bf16x8 v; } c0, c1;                                   \
  c0.us[0]=f2bf((UA).x); c0.us[1]=f2bf((UA).y); c0.us[2]=f2bf((UA).z); c0.us[3]=f2bf((UA).w); \
  c0.us[4]=f2bf((UB).x); c0.us[5]=f2bf((UB).y); c0.us[6]=f2bf((UB).z); c0.us[7]=f2bf((UB).w); \
  c1.us[0]=f2bf((UC).x); c1.us[1]=f2bf((UC).y); c1.us[2]=f2bf((UC).z); c1.us[3]=f2bf((UC).w); \
  c1.us[4]=0; c1.us[5]=0; c1.us[6]=0; c1.us[7]=0;                               \
  _Pragma("unroll")                                                             \
  for (int q = 0; q < 2; ++q){                                                  \
    f32x4 acc = {0.f,0.f,0.f,0.f};                                              \
    acc = mfma16(lwf[q*2+0], c0.v, acc);                                        \
    acc = mfma16(lwf[q*2+1], c1.v, acc);                                        \
    _Pragma("unroll")                                                           \
    for (int r = 0; r < 4; ++r) w[q*4+r] = lamr[q*4+r]*w[q*4+r] + acc[r];       \
  }                                                                             \
  if ((((TT) & 7) == 7) && ((TT) < T_-1)){                                      \
    const int c2 = ((TT)+1) >> 3;                                               \
    _Pragma("unroll")                                                           \
    for (int q = 0; q < 2; ++q){                                                \
      const int i = (itb+q)*16 + 4*lh;                                          \
      ushort4 o; o.x=f2bf(w[q*4+0]); o.y=f2bf(w[q*4+1]); o.z=f2bf(w[q*4+2]); o.w=f2bf(w[q*4+3]); \
      *(ushort4*)(Wchk + ((size_t)c2*B_ + row)*D_ + i) = o;                     \
    }                                                                           \
  }                                                                             \
} while(0)

__global__ void __launch_bounds__(256) k_scan(const float* __restrict__ U,
    const ushort_t* __restrict__ Lws, const float* __restrict__ lam,
    ushort_t* __restrict__ Wchk){
  const int tid = threadIdx.x;
  const int wid = tid >> 6, l = tid & 63;
  const int lm = l & 15, lh = l >> 4;
  const int bq = blockIdx.x >> 1, ih = blockIdx.x & 1;
  const int b0 = bq * 16;
  const int row = b0 + lm;
  const int itb = ih*8 + wid*2;

  bf16x8 lwf[4];
  #pragma unroll
  for (int q = 0; q < 2; ++q)
    #pragma unroll
    for (int c = 0; c < 2; ++c)
      lwf[q*2 + c] = *(const bf16x8*)(Lws + ((size_t)(((itb+q)*2 + c)*64 + l))*8);

  float lamr[8], w[8];
  #pragma unroll
  for (int q = 0; q < 2; ++q){
    const int i = (itb+q)*16 + 4*lh;
    const float4 lv = *(const float4*)&lam[i];
    const ushort4 wu = *(const ushort4*)(Wchk + (size_t)row*D_ + i);
    lamr[q*4+0]=lv.x; lamr[q*4+1]=lv.y; lamr[q*4+2]=lv.z; lamr[q*4+3]=lv.w;
    w[q*4+0]=bf2f(wu.x); w[q*4+1]=bf2f(wu.y); w[q*4+2]=bf2f(wu.z); w[q*4+3]=bf2f(wu.w);
  }

  const size_t TS = (size_t)B_ * UD_;
  const float* Urow = U + (size_t)row * UD_;
  float4 Aa, Ab, Ac, Ba, Bb, Bc;
  Aa = *(const float4*)&Urow[4*lh]; Ab = *(const float4*)&Urow[16+4*lh]; Ac = *(const float4*)&Urow[32+4*lh];
  { const float* Up = Urow + TS;
    Ba = *(const float4*)&Up[4*lh]; Bb = *(const float4*)&Up[16+4*lh]; Bc = *(const float4*)&Up[32+4*lh]; }

  #pragma unroll 1
  for (int tt = 0; tt < 64; ++tt){
    const int t0 = 2*tt;
    SCAN_STEP(Aa, Ab, Ac, t0);
    if (t0 + 2 < T_){
      const float* Up = Urow + (size_t)(t0+2)*TS;
      Aa = *(const float4*)&Up[4*lh]; Ab = *(const float4*)&Up[16+4*lh]; Ac = *(const float4*)&Up[32+4*lh];
    }
    SCAN_STEP(Ba, Bb, Bc, t0+1);
    if (t0 + 3 < T_){
      const float* Up = Urow + (size_t)(t0+3)*TS;
      Ba = *(const float4*)&Up[4*lh]; Bb = *(const float4*)&Up[16+4*lh]; Bc = *(const float4*)&Up[32+4*lh];
    }
  }
}

// ---------------- fused replay + output GEMM (STEP-PAIRED, reg-trimmed) ----------------
// Round-8's pairing regressed +30us vs unpaired: suspected VGPR spill from the
// cvA union array (32 regs) + copy-out the allocator can't coalesce. This version
// packs wfrA/wfrB DIRECTLY into uint4 words (compile-time .x/.y/.z/.w selection),
// removes all union arrays, and delays the next-pair u prefetch until after wfr
// packing. Structure otherwise identical to round 8.
__global__ void __launch_bounds__(256) k_fused(
    const float* __restrict__ U, const ushort_t* __restrict__ Af,
    const ushort_t* __restrict__ Lws, const float* __restrict__ lam,
    const float* __restrict__ dVd, const ushort_t* __restrict__ Wchk,
    float* __restrict__ outZ, float* __restrict__ outY){
  __shared__ __align__(16) ushort_t AfZhL[8*8*512];   // 65536 B
  __shared__ __align__(16) ushort_t LwsL[32*512];     // 32768 B
  __shared__ __align__(16) ushort_t AfYhL[40*512];    // 40960 B
  __shared__ __align__(16) float    trbZ[4][16][68];  // 17408 B
  __shared__ __align__(16) float    dVdL[128];        // 512 B
  __shared__ __align__(16) float    lamL[256];        // 1024 B

  const int tid = threadIdx.x;
  const int bid = blockIdx.x;
  const int h  = bid & 1;
  const int ch = (bid >> 1) & 15;
  const int bq = bid >> 5;
  const int wid = tid >> 6, l = tid & 63;
  const int lm = l & 15, lh = l >> 4;
  const int col0 = bq*64 + wid*16;
  const int col = col0 + lm;

  // one-time staging
  {
    const uint4* gsrc = (const uint4*)Af;
    uint4* dz = (uint4*)AfZhL;
    #pragma unroll
    for (int r = 0; r < 16; ++r){
      const int i = r*256 + tid;
      const int f = i >> 6, l4 = i & 63;
      const int mi8 = f >> 3, kc = f & 7;
      dz[i] = gsrc[(size_t)((h*8 + mi8)*10 + kc)*64 + l4];
    }
    uint4* dy = (uint4*)AfYhL;
    const int nY = h ? 640 : 2560;
    const int sb = 16 + (h ? 4 : 0);
    #pragma unroll
    for (int r = 0; r < 10; ++r){
      const int i = r*256 + tid;
      if (i < nY){
        const int f = i >> 6, l4 = i & 63;
        const int myl = f / 10, j = f % 10;
        dy[i] = gsrc[(size_t)((sb + myl)*10 + j)*64 + l4];
      }
    }
    const uint4* ls = (const uint4*)Lws;
    uint4* ld = (uint4*)LwsL;
    #pragma unroll
    for (int r = 0; r < 8; ++r) ld[r*256 + tid] = ls[r*256 + tid];
    if (tid < 32) ((float4*)dVdL)[tid] = ((const float4*)(dVd + h*128))[tid];
    else if (tid < 96) ((float4*)lamL)[tid-32] = ((const float4*)lam)[tid-32];
  }

  // boundary w
  float w[64];
  #pragma unroll
  for (int kc = 0; kc < 8; ++kc)
    #pragma unroll
    for (int hh = 0; hh < 2; ++hh){
      const int i = 32*kc + 16*hh + 4*lh;
      const ushort4 wu = *(const ushort4*)(Wchk + ((size_t)ch*B_ + col)*D_ + i);
      const int e = 8*kc + 4*hh;
      w[e+0]=bf2f(wu.x); w[e+1]=bf2f(wu.y); w[e+2]=bf2f(wu.z); w[e+3]=bf2f(wu.w);
    }

  // u prefetch for pair 0
  const size_t TS = (size_t)B_ * UD_;
  const float* Ucol = U + (size_t)col * UD_;
  float4 uaA, ubA, ucA, uaB, ubB, ucB;
  {
    const float* Ut = Ucol + (size_t)(ch*8)*TS;
    uaA = *(const float4*)&Ut[4*lh]; ubA = *(const float4*)&Ut[16+4*lh]; ucA = *(const float4*)&Ut[32+4*lh];
    const float* Ut1 = Ut + TS;
    uaB = *(const float4*)&Ut1[4*lh]; ubB = *(const float4*)&Ut1[16+4*lh]; ucB = *(const float4*)&Ut1[32+4*lh];
  }

  __syncthreads();   // the only block-wide barrier

#define ZLOOP(HH)                                                               \
  { float* zA = outZ + ((size_t)t*B_ + col0)*D_ + (HH)*128;                     \
    float* zB = zA + (size_t)B_*D_;                                             \
    _Pragma("unroll")                                                           \
    for (int g = 0; g < 4; ++g){                                                \
      _Pragma("unroll")                                                         \
      for (int mi = 0; mi < 2; ++mi){                                           \
        const int mi8 = g*2 + mi;                                               \
        f32x4 aA = {0.f,0.f,0.f,0.f}, aB = {0.f,0.f,0.f,0.f};                   \
        _Pragma("unroll")                                                       \
        for (int kc = 0; kc < 8; ++kc){                                         \
          const bf16x8 af = *(const bf16x8*)&AfZhL[((mi8*8+kc)*64 + l)*8];      \
          aA = mfma16(af, BFV(wfrAu[kc]), aA);                                  \
          aB = mfma16(af, BFV(wfrBu[kc]), aB);                                  \
        }                                                                       \
        const float4 dv = *(const float4*)&dVdL[mi8*16 + 4*lh];                 \
        _Pragma("unroll")                                                       \
        for (int r = 0; r < 4; ++r){                                            \
          aA[r] += ((const float*)&dv)[r] * (float)BFV(wfrAu[(HH)*4+(mi8>>1)])[r + 4*(mi8&1)]; \
          aB[r] += ((const float*)&dv)[r] * (float)BFV(wfrBu[(HH)*4+(mi8>>1)])[r + 4*(mi8&1)]; \
        }                                                                       \
        *(float4*)&trbZ[wid][lm][mi*16 + 4*lh] = make_float4(aA[0],aA[1],aA[2],aA[3]); \
        *(float4*)&trbZ[wid][lm][32 + mi*16 + 4*lh] = make_float4(aB[0],aB[1],aB[2],aB[3]); \
      }                                                                         \
      __builtin_amdgcn_wave_barrier();                                          \
      _Pragma("unroll")                                                         \
      for (int j = 0; j < 4; ++j){                                              \
        const int stp = j >> 1, jr = (j & 1)*8;                                 \
        const int r_ = jr + (l >> 3), c8 = l & 7;                               \
        const float4 v = *(const float4*)&trbZ[wid][r_][stp*32 + 4*c8];         \
        float* dst = stp ? zB : zA;                                             \
        *(float4*)&dst[(size_t)r_*D_ + g*32 + 4*c8] = v;                        \
      }                                                                         \
      __builtin_amdgcn_wave_barrier();                                          \
    } }

#define YLOOP(COFF, NMY)                                                        \
  { float* yA = outY + ((size_t)t*B_ + col)*NO_ + (COFF);                       \
    float* yB = yA + (size_t)B_*NO_;                                            \
    _Pragma("unroll")                                                           \
    for (int my = 0; my < (NMY); ++my){                                         \
      f32x4 aA = {0.f,0.f,0.f,0.f}, aB = {0.f,0.f,0.f,0.f};                     \
      _Pragma("unroll")                                                         \
      for (int kc = 0; kc < 8; ++kc){                                           \
        const bf16x8 af = *(const bf16x8*)&AfYhL[((my*10+kc)*64 + l)*8];        \
        aA = mfma16(af, BFV(wfrAu[kc]), aA);                                    \
        aB = mfma16(af, BFV(wfrBu[kc]), aB);                                    \
      }                                                                         \
      { const bf16x8 af8 = *(const bf16x8*)&AfYhL[((my*10+8)*64 + l)*8];        \
        const bf16x8 af9 = *(const bf16x8*)&AfYhL[((my*10+9)*64 + l)*8];        \
        aA = mfma16(af8, ufA0, aA); aA = mfma16(af9, ufA1, aA);                 \
        aB = mfma16(af8, ufB0, aB); aB = mfma16(af9, ufB1, aB); }               \
      *(float4*)&yA[my*16 + 4*lh] = make_float4(aA[0],aA[1],aA[2],aA[3]);       \
      *(float4*)&yB[my*16 + 4*lh] = make_float4(aB[0],aB[1],aB[2],aB[3]);       \
    } }

  #pragma unroll 1
  for (int p = 0; p < 4; ++p){
    const int t = ch*8 + 2*p;
    // build u fragments for both steps (direct uint4 packing, no unions)
    const uint4 a0u = { pack2bf(uaA.x,uaA.y), pack2bf(uaA.z,uaA.w),
                        pack2bf(ubA.x,ubA.y), pack2bf(ubA.z,ubA.w) };
    const uint4 a1u = { pack2bf(ucA.x,ucA.y), pack2bf(ucA.z,ucA.w), 0u, 0u };
    const uint4 b0u = { pack2bf(uaB.x,uaB.y), pack2bf(uaB.z,uaB.w),
                        pack2bf(ubB.x,ubB.y), pack2bf(ubB.z,ubB.w) };
    const uint4 b1u = { pack2bf(ucB.x,ucB.y), pack2bf(ucB.z,ucB.w), 0u, 0u };
    const bf16x8 ufA0 = BFV(a0u), ufA1 = BFV(a1u);
    const bf16x8 ufB0 = BFV(b0u), ufB1 = BFV(b1u);

    // interleaved scan: each LwsL fragment read once, both steps advanced;
    // wfrA packed DIRECTLY into uint4 words (compile-time selection).
    uint4 wfrAu[8], wfrBu[8];
    #pragma unroll
    for (int it = 0; it < 16; ++it){
      const bf16x8 a0 = *(const bf16x8*)&LwsL[((it*2+0)*64 + l)*8];
      const bf16x8 a1 = *(const bf16x8*)&LwsL[((it*2+1)*64 + l)*8];
      const float4 lv = *(const float4*)&lamL[32*(it>>1) + 16*(it&1) + 4*lh];
      f32x4 pA = {0.f,0.f,0.f,0.f};
      pA = mfma16(a0, ufA0, pA);
      pA = mfma16(a1, ufA1, pA);
      f32x4 pB = {0.f,0.f,0.f,0.f};
      pB = mfma16(a0, ufB0, pB);
      pB = mfma16(a1, ufB1, pB);
      const int e0 = 8*(it>>1) + 4*(it&1);
      const float wa0 = lv.x*w[e0+0] + pA[0];
      const float wa1 = lv.y*w[e0+1] + pA[1];
      const float wa2 = lv.z*w[e0+2] + pA[2];
      const float wa3 = lv.w*w[e0+3] + pA[3];
      w[e0+0] = lv.x*wa0 + pB[0];
      w[e0+1] = lv.y*wa1 + pB[1];
      w[e0+2] = lv.z*wa2 + pB[2];
      w[e0+3] = lv.w*wa3 + pB[3];
      const unsigned p0 = pack2bf(wa0, wa1);
      const unsigned p1 = pack2bf(wa2, wa3);
      const int kc = it >> 1;
      if ((it & 1) == 0){ wfrAu[kc].x = p0; wfrAu[kc].y = p1; }
      else              { wfrAu[kc].z = p0; wfrAu[kc].w = p1; }
    }
    #pragma unroll
    for (int kc = 0; kc < 8; ++kc){
      wfrBu[kc].x = pack2bf(w[8*kc+0], w[8*kc+1]);
      wfrBu[kc].y = pack2bf(w[8*kc+2], w[8*kc+3]);
      wfrBu[kc].z = pack2bf(w[8*kc+4], w[8*kc+5]);
      wfrBu[kc].w = pack2bf(w[8*kc+6], w[8*kc+7]);
    }
    // prefetch next pair's u AFTER packing (short live range; covered by Z/Y)
    if (p < 3){
      const float* Ut = Ucol + (size_t)(t+2)*TS;
      uaA = *(const float4*)&Ut[4*lh]; ubA = *(const float4*)&Ut[16+4*lh]; ucA = *(const float4*)&Ut[32+4*lh];
      const float* Ut1 = Ut + TS;
      uaB = *(const float4*)&Ut1[4*lh]; ubB = *(const float4*)&Ut1[16+4*lh]; ucB = *(const float4*)&Ut1[32+4*lh];
    }
    // output GEMMs for both steps (A-frags read once)
    if (h == 0){
      ZLOOP(0);
      YLOOP(0, 4);
    } else {
      ZLOOP(1);
      YLOOP(64, 1);
    }
  }
#undef ZLOOP
#undef YLOOP
}

// ---------------- launcher ----------------
extern "C" void kernel_launch(void* const* d_in, const int* in_sizes, int n_in,
                              void* d_out, int out_size, void* d_ws, size_t ws_size,
                              hipStream_t stream){
  const float* z0  = (const float*)d_in[0];
  const float* dt  = (const float*)d_in[2];
  const float* U   = (const float*)d_in[3];
  const float* eig = (const float*)d_in[4];
  const float* V   = (const float*)d_in[5];
  const float* L   = (const float*)d_in[6];
  const float* C   = (const float*)d_in[7];
  const float* Dm  = (const float*)d_in[8];
  float* outZ = (float*)d_out;
  float* outY = outZ + (size_t)T_*B_*D_;

  char* ws = (char*)d_ws;
  float* Xa    = (float*)(ws + 0);        // later reused as VinvT
  float* Xb    = (float*)(ws + 262144);
  float* Tt    = (float*)(ws + 524288);
  float* Lw    = (float*)(ws + 786432);
  float* Cw    = (float*)(ws + 835584);
  float* lam   = (float*)(ws + 917504);
  float* dVd   = (float*)(ws + 918528);
  ushort_t* Af   = (ushort_t*)(ws + 919552);
  ushort_t* Lws  = (ushort_t*)(ws + 1134592);
  ushort_t* Wchk = (ushort_t*)(ws + 1167360);
  if (ws_size < 17944576u) return;

  k_init<<<256,256,0,stream>>>(V, eig, Xa, lam);
  // Newton-Schulz, 3 iters from X0 = 2I - V  -> Vinv = Xb
  k_mm_mul<<<256,256,0,stream>>>(V, Xa, Tt);
  k_mm_upd<<<256,256,0,stream>>>(Xa, Tt, Xb);
  k_mm_mul<<<256,256,0,stream>>>(V, Xb, Tt);
  k_mm_upd<<<256,256,0,stream>>>(Xb, Tt, Xa);
  k_mm_mul<<<256,256,0,stream>>>(V, Xa, Tt);
  k_mm_upd<<<256,256,0,stream>>>(Xa, Tt, Xb);
  k_prep1<<<592,256,0,stream>>>(Xb, V, L, C, dt, /*VinvT=*/Xa, Lw, Cw, dVd);
  k_prep2<<<288,256,0,stream>>>(z0, /*VinvT=*/Xa, Lw, Wchk, Lws);
  k_packA<<<210,64,0,stream>>>(V, Cw, Dm, dt, Af);
  k_scan<<<256,256,0,stream>>>(U, Lws, lam, Wchk);
  k_fused<<<1024,256,0,stream>>>(U, Af, Lws, lam, dVd, Wchk, outZ, outY);
}

// Round 10
// 279.712 us; speedup vs baseline: 1.9293x; 1.0252x over previous
//
#include <hip/hip_runtime.h>

#define D_   256
#define UD_  48
#define NO_  80
#define T_   128
#define B_   2048

typedef __bf16 bf16x8 __attribute__((ext_vector_type(8)));
typedef float  f32x4  __attribute__((ext_vector_type(4)));
typedef unsigned short ushort_t;

static __device__ __forceinline__ ushort_t f2bf(float f){
  return __builtin_bit_cast(ushort_t, (__bf16)f);
}
static __device__ __forceinline__ float bf2f(ushort_t u){
  union { unsigned int i; float f; } c; c.i = ((unsigned int)u) << 16; return c.f;
}
static __device__ __forceinline__ f32x4 mfma16(bf16x8 a, bf16x8 b, f32x4 c){
  return __builtin_amdgcn_mfma_f32_16x16x32_bf16(a, b, c, 0, 0, 0);
}

// ---------------- prep: 4 kernels (was 8) ----------------
// NS iter1 closed form: X1 = 4I - 6V + 4W - V@W, W = V^2  (absorbs k_init).
// 2 NS iterations total: error ||(I-V)^2||^4 ~ 1e-4 rel << bf16 noise 4e-3.

// W = V@V (blocks 0..255) | Cw = C@V (256..335) | lam,dVd (336)
__global__ void __launch_bounds__(256) k_pre(
    const float* __restrict__ V, const float* __restrict__ eig,
    const float* __restrict__ Cmat,
    float* __restrict__ W, float* __restrict__ Cw,
    float* __restrict__ lam, float* __restrict__ dVd){
  const int bid = blockIdx.x, tid = threadIdx.x;
  if (bid < 256){
    const float* Ar = V + bid*D_;
    float a0=0.f,a1=0.f,a2=0.f,a3=0.f;
    #pragma unroll 4
    for (int k = 0; k < D_; k += 4){
      a0 += Ar[k+0] * V[(k+0)*D_ + tid];
      a1 += Ar[k+1] * V[(k+1)*D_ + tid];
      a2 += Ar[k+2] * V[(k+2)*D_ + tid];
      a3 += Ar[k+3] * V[(k+3)*D_ + tid];
    }
    W[bid*D_ + tid] = (a0+a1)+(a2+a3);
  } else if (bid < 256 + NO_){
    const int n = bid - 256;
    float acc = 0.f;
    #pragma unroll 4
    for (int j = 0; j < D_; ++j) acc += Cmat[n*D_ + j] * V[j*D_ + tid];
    Cw[n*D_ + tid] = acc;
  } else {
    lam[tid] = 0.99f / (1.0f + expf(-eig[tid]));
    const float v = V[tid*D_ + tid];
    dVd[tid] = v - bf2f(f2bf(v));
  }
}

// X1 = 4I - 6V + 4W - V@W
__global__ void __launch_bounds__(256) k_x1(
    const float* __restrict__ V, const float* __restrict__ W,
    float* __restrict__ X1){
  const int i = blockIdx.x, j = threadIdx.x;
  const float* Ar = V + i*D_;
  float a0=0.f,a1=0.f,a2=0.f,a3=0.f;
  #pragma unroll 4
  for (int k = 0; k < D_; k += 4){
    a0 += Ar[k+0] * W[(k+0)*D_ + j];
    a1 += Ar[k+1] * W[(k+1)*D_ + j];
    a2 += Ar[k+2] * W[(k+2)*D_ + j];
    a3 += Ar[k+3] * W[(k+3)*D_ + j];
  }
  X1[i*D_ + j] = (i == j ? 4.0f : 0.0f) - 6.0f*V[i*D_ + j] + 4.0f*W[i*D_ + j]
                 - ((a0+a1)+(a2+a3));
}

// T = V@X1 (classic mm)
__global__ void __launch_bounds__(256) k_mm_mul(
    const float* __restrict__ A, const float* __restrict__ B,
    float* __restrict__ Cm){
  const int i = blockIdx.x, j = threadIdx.x;
  const float* Ar = A + i*D_;
  float a0=0.f,a1=0.f,a2=0.f,a3=0.f;
  #pragma unroll 4
  for (int k = 0; k < D_; k += 4){
    a0 += Ar[k+0] * B[(k+0)*D_ + j];
    a1 += Ar[k+1] * B[(k+1)*D_ + j];
    a2 += Ar[k+2] * B[(k+2)*D_ + j];
    a3 += Ar[k+3] * B[(k+3)*D_ + j];
  }
  Cm[i*D_ + j] = (a0+a1)+(a2+a3);
}

// X2 = 2*X1 - X1@T = Vinv. Writes VinvT (scatter) + Lw = dt*Vinv@L (row in LDS).
__global__ void __launch_bounds__(256) k_x2(
    const float* __restrict__ X1, const float* __restrict__ Tm,
    const float* __restrict__ Lmat, const float* __restrict__ dt,
    float* __restrict__ VinvT, float* __restrict__ Lw){
  __shared__ float row[256];
  const int i = blockIdx.x, j = threadIdx.x;
  const float* Xr = X1 + i*D_;
  float a0=0.f,a1=0.f,a2=0.f,a3=0.f;
  #pragma unroll 4
  for (int k = 0; k < D_; k += 4){
    a0 += Xr[k+0] * Tm[(k+0)*D_ + j];
    a1 += Xr[k+1] * Tm[(k+1)*D_ + j];
    a2 += Xr[k+2] * Tm[(k+2)*D_ + j];
    a3 += Xr[k+3] * Tm[(k+3)*D_ + j];
  }
  const float out = 2.0f*Xr[j] - ((a0+a1)+(a2+a3));
  VinvT[j*D_ + i] = out;
  row[j] = out;
  __syncthreads();
  if (j < UD_){
    float acc = 0.f;
    #pragma unroll 4
    for (int k = 0; k < D_; ++k) acc += row[k] * Lmat[k*UD_ + j];
    Lw[i*UD_ + j] = acc * dt[0];
  }
}

// w0 = z0@VinvT (blocks 0..255) | Lws pack (256..287) | packA (288..341)
__global__ void __launch_bounds__(256) k_prep2(
    const float* __restrict__ z0, const float* __restrict__ VinvT,
    const float* __restrict__ Lw, const float* __restrict__ V,
    const float* __restrict__ Cw, const float* __restrict__ Dmat,
    const float* __restrict__ dt,
    ushort_t* __restrict__ Wchk, ushort_t* __restrict__ Lws,
    ushort_t* __restrict__ Af){
  __shared__ float zr[8][256];
  const int bid = blockIdx.x, tid = threadIdx.x;
  if (bid < 256){
    const int b0 = bid * 8;
    #pragma unroll
    for (int r = 0; r < 8; ++r) zr[r][tid] = z0[(size_t)(b0+r)*D_ + tid];
    __syncthreads();
    float acc[8] = {0.f,0.f,0.f,0.f,0.f,0.f,0.f,0.f};
    #pragma unroll 4
    for (int j = 0; j < D_; ++j){
      const float vj = VinvT[j*D_ + tid];
      #pragma unroll
      for (int r = 0; r < 8; ++r) acc[r] += zr[r][j] * vj;
    }
    #pragma unroll
    for (int r = 0; r < 8; ++r)
      Wchk[(size_t)(b0+r)*D_ + tid] = f2bf(acc[r]);
  } else if (bid < 288){
    const int f = bid - 256;
    if (tid < 64){
      const int l = tid, lm = l & 15, lh = l >> 4;
      const int it = f >> 1, kc2 = f & 1;
      const int ig = it*16 + lm;
      #pragma unroll
      for (int j = 0; j < 8; ++j){
        const int k = 32*kc2 + 4*lh + (j & 3) + 16*(j >> 2);
        Lws[(f*64 + l)*8 + j] = f2bf(k < UD_ ? Lw[ig*UD_ + k] : 0.f);
      }
    }
  } else {
    const int v = (bid - 288)*4 + (tid >> 6);
    if (v < 210){
      const int mt = v / 10, kc = v % 10;
      const int l = tid & 63, lm = l & 15, lh = l >> 4;
      const float dts = dt[0];
      #pragma unroll
      for (int j = 0; j < 8; ++j){
        const int k = 32*kc + 4*lh + (j & 3) + 16*(j >> 2);
        float val = 0.f;
        if (mt < 16){
          if (kc < 8) val = V[(mt*16 + lm)*D_ + k];
        } else {
          const int n = (mt - 16)*16 + lm;
          if (kc < 8) val = Cw[n*D_ + k];
          else { const int ku = k - 256; if (ku < UD_) val = dts * Dmat[n*UD_ + ku]; }
        }
        Af[((size_t)(mt*10 + kc)*64 + l)*8 + j] = f2bf(val);
      }
    }
  }
}

// ---------------- boundary scan: 128 blocks, wave owns 4 eigen-blocks ----------------
// (halves duplicated U reads vs the 256-block 2-ih version)
#define SCAN_STEP4(UA, UB, UC, TT) do {                                         \
  union { ushort_t us[8]; bf16x8 v; } c0, c1;                                   \
  c0.us[0]=f2bf((UA).x); c0.us[1]=f2bf((UA).y); c0.us[2]=f2bf((UA).z); c0.us[3]=f2bf((UA).w); \
  c0.us[4]=f2bf((UB).x); c0.us[5]=f2bf((UB).y); c0.us[6]=f2bf((UB).z); c0.us[7]=f2bf((UB).w); \
  c1.us[0]=f2bf((UC).x); c1.us[1]=f2bf((UC).y); c1.us[2]=f2bf((UC).z); c1.us[3]=f2bf((UC).w); \
  c1.us[4]=0; c1.us[5]=0; c1.us[6]=0; c1.us[7]=0;                               \
  _Pragma("unroll")                                                             \
  for (int q = 0; q < 4; ++q){                                                  \
    f32x4 acc = {0.f,0.f,0.f,0.f};                                              \
    acc = mfma16(lwf[q*2+0], c0.v, acc);                                        \
    acc = mfma16(lwf[q*2+1], c1.v, acc);                                        \
    _Pragma("unroll")                                                           \
    for (int r = 0; r < 4; ++r) w[q*4+r] = lamr[q*4+r]*w[q*4+r] + acc[r];       \
  }                                                                             \
  if ((((TT) & 7) == 7) && ((TT) < T_-1)){                                      \
    const int c2 = ((TT)+1) >> 3;                                               \
    _Pragma("unroll")                                                           \
    for (int q = 0; q < 4; ++q){                                                \
      const int i = (itb+q)*16 + 4*lh;                                          \
      ushort4 o; o.x=f2bf(w[q*4+0]); o.y=f2bf(w[q*4+1]); o.z=f2bf(w[q*4+2]); o.w=f2bf(w[q*4+3]); \
      *(ushort4*)(Wchk + ((size_t)c2*B_ + row)*D_ + i) = o;                     \
    }                                                                           \
  }                                                                             \
} while(0)

__global__ void __launch_bounds__(256) k_scan(const float* __restrict__ U,
    const ushort_t* __restrict__ Lws, const float* __restrict__ lam,
    ushort_t* __restrict__ Wchk){
  const int tid = threadIdx.x;
  const int wid = tid >> 6, l = tid & 63;
  const int lm = l & 15, lh = l >> 4;
  const int b0 = blockIdx.x * 16;
  const int row = b0 + lm;
  const int itb = wid*4;               // wave covers 4 it-blocks = 64 dims

  bf16x8 lwf[8];
  #pragma unroll
  for (int q = 0; q < 4; ++q)
    #pragma unroll
    for (int c = 0; c < 2; ++c)
      lwf[q*2 + c] = *(const bf16x8*)(Lws + ((size_t)(((itb+q)*2 + c)*64 + l))*8);

  float lamr[16], w[16];
  #pragma unroll
  for (int q = 0; q < 4; ++q){
    const int i = (itb+q)*16 + 4*lh;
    const float4 lv = *(const float4*)&lam[i];
    const ushort4 wu = *(const ushort4*)(Wchk + (size_t)row*D_ + i);
    lamr[q*4+0]=lv.x; lamr[q*4+1]=lv.y; lamr[q*4+2]=lv.z; lamr[q*4+3]=lv.w;
    w[q*4+0]=bf2f(wu.x); w[q*4+1]=bf2f(wu.y); w[q*4+2]=bf2f(wu.z); w[q*4+3]=bf2f(wu.w);
  }

  const size_t TS = (size_t)B_ * UD_;
  const float* Urow = U + (size_t)row * UD_;
  float4 Aa, Ab, Ac, Ba, Bb, Bc;
  Aa = *(const float4*)&Urow[4*lh]; Ab = *(const float4*)&Urow[16+4*lh]; Ac = *(const float4*)&Urow[32+4*lh];
  { const float* Up = Urow + TS;
    Ba = *(const float4*)&Up[4*lh]; Bb = *(const float4*)&Up[16+4*lh]; Bc = *(const float4*)&Up[32+4*lh]; }

  #pragma unroll 1
  for (int tt = 0; tt < 64; ++tt){
    const int t0 = 2*tt;
    SCAN_STEP4(Aa, Ab, Ac, t0);
    if (t0 + 2 < T_){
      const float* Up = Urow + (size_t)(t0+2)*TS;
      Aa = *(const float4*)&Up[4*lh]; Ab = *(const float4*)&Up[16+4*lh]; Ac = *(const float4*)&Up[32+4*lh];
    }
    SCAN_STEP4(Ba, Bb, Bc, t0+1);
    if (t0 + 3 < T_){
      const float* Up = Urow + (size_t)(t0+3)*TS;
      Ba = *(const float4*)&Up[4*lh]; Bb = *(const float4*)&Up[16+4*lh]; Bc = *(const float4*)&Up[32+4*lh];
    }
  }
}

// ---------------- fused replay + output GEMM (round-6 version, F~144us) ----------------
// Unpaired (rounds 8/9 proved step-pairing loses ~20-30us). 1024 blocks =
// 32 bq x 16 ch x 2 h (h low bit). Y split 64/16. LDS h-max 158208 B.
__global__ void __launch_bounds__(256) k_fused(
    const float* __restrict__ U, const ushort_t* __restrict__ Af,
    const ushort_t* __restrict__ Lws, const float* __restrict__ lam,
    const float* __restrict__ dVd, const ushort_t* __restrict__ Wchk,
    float* __restrict__ outZ, float* __restrict__ outY){
  __shared__ __align__(16) ushort_t AfZhL[8*8*512];   // 65536 B
  __shared__ __align__(16) ushort_t LwsL[32*512];     // 32768 B
  __shared__ __align__(16) ushort_t AfYhL[40*512];    // 40960 B
  __shared__ __align__(16) float    trbZ[4][16][68];  // 17408 B
  __shared__ __align__(16) float    dVdL[128];        // 512 B
  __shared__ __align__(16) float    lamL[256];        // 1024 B

  const int tid = threadIdx.x;
  const int bid = blockIdx.x;
  const int h  = bid & 1;
  const int ch = (bid >> 1) & 15;
  const int bq = bid >> 5;
  const int wid = tid >> 6, l = tid & 63;
  const int lm = l & 15, lh = l >> 4;
  const int col0 = bq*64 + wid*16;
  const int col = col0 + lm;

  // one-time staging
  {
    const uint4* gsrc = (const uint4*)Af;
    uint4* dz = (uint4*)AfZhL;
    #pragma unroll
    for (int r = 0; r < 16; ++r){
      const int i = r*256 + tid;
      const int f = i >> 6, l4 = i & 63;
      const int mi8 = f >> 3, kc = f & 7;
      dz[i] = gsrc[(size_t)((h*8 + mi8)*10 + kc)*64 + l4];
    }
    uint4* dy = (uint4*)AfYhL;
    const int nY = h ? 640 : 2560;
    const int sb = 16 + (h ? 4 : 0);
    #pragma unroll
    for (int r = 0; r < 10; ++r){
      const int i = r*256 + tid;
      if (i < nY){
        const int f = i >> 6, l4 = i & 63;
        const int myl = f / 10, j = f % 10;
        dy[i] = gsrc[(size_t)((sb + myl)*10 + j)*64 + l4];
      }
    }
    const uint4* ls = (const uint4*)Lws;
    uint4* ld = (uint4*)LwsL;
    #pragma unroll
    for (int r = 0; r < 8; ++r) ld[r*256 + tid] = ls[r*256 + tid];
    if (tid < 32) ((float4*)dVdL)[tid] = ((const float4*)(dVd + h*128))[tid];
    else if (tid < 96) ((float4*)lamL)[tid-32] = ((const float4*)lam)[tid-32];
  }

  // boundary w
  float w[64];
  #pragma unroll
  for (int kc = 0; kc < 8; ++kc)
    #pragma unroll
    for (int hh = 0; hh < 2; ++hh){
      const int i = 32*kc + 16*hh + 4*lh;
      const ushort4 wu = *(const ushort4*)(Wchk + ((size_t)ch*B_ + col)*D_ + i);
      const int e = 8*kc + 4*hh;
      w[e+0]=bf2f(wu.x); w[e+1]=bf2f(wu.y); w[e+2]=bf2f(wu.z); w[e+3]=bf2f(wu.w);
    }

  // u prefetch
  const size_t TS = (size_t)B_ * UD_;
  const float* Ucol = U + (size_t)col * UD_;
  float4 ua, ub, uc;
  {
    const float* Ut = Ucol + (size_t)(ch*8)*TS;
    ua = *(const float4*)&Ut[4*lh]; ub = *(const float4*)&Ut[16+4*lh]; uc = *(const float4*)&Ut[32+4*lh];
  }

  __syncthreads();   // the only block-wide barrier

#define ZLOOP(HH)                                                               \
  { float* zbase = outZ + ((size_t)t*B_ + col0)*D_ + (HH)*128;                  \
    _Pragma("unroll")                                                           \
    for (int g = 0; g < 2; ++g){                                                \
      _Pragma("unroll")                                                         \
      for (int mi = 0; mi < 4; ++mi){                                           \
        const int mi8 = g*4 + mi;                                               \
        f32x4 acc = {0.f,0.f,0.f,0.f};                                          \
        _Pragma("unroll")                                                       \
        for (int kc = 0; kc < 8; ++kc){                                         \
          const bf16x8 af = *(const bf16x8*)&AfZhL[((mi8*8+kc)*64 + l)*8];      \
          acc = mfma16(af, wfr[kc], acc);                                       \
        }                                                                       \
        const float4 dv = *(const float4*)&dVdL[mi8*16 + 4*lh];                 \
        acc[0] += dv.x * (float)wfr[((HH)*8+mi8)>>1][0 + 4*(mi8&1)];            \
        acc[1] += dv.y * (float)wfr[((HH)*8+mi8)>>1][1 + 4*(mi8&1)];            \
        acc[2] += dv.z * (float)wfr[((HH)*8+mi8)>>1][2 + 4*(mi8&1)];            \
        acc[3] += dv.w * (float)wfr[((HH)*8+mi8)>>1][3 + 4*(mi8&1)];            \
        *(float4*)&trbZ[wid][lm][mi*16 + 4*lh] = make_float4(acc[0],acc[1],acc[2],acc[3]); \
      }                                                                         \
      __builtin_amdgcn_wave_barrier();                                          \
      _Pragma("unroll")                                                         \
      for (int j = 0; j < 4; ++j){                                              \
        const int r_ = j*4 + (l >> 4), c16 = l & 15;                            \
        const float4 v = *(const float4*)&trbZ[wid][r_][4*c16];                 \
        *(float4*)&zbase[(size_t)r_*D_ + g*64 + 4*c16] = v;                     \
      }                                                                         \
      __builtin_amdgcn_wave_barrier();                                          \
    } }

#define YLOOP(COFF, NMY)                                                        \
  { float* yrow = outY + ((size_t)t*B_ + col)*NO_ + (COFF);                     \
    _Pragma("unroll")                                                           \
    for (int my = 0; my < (NMY); ++my){                                         \
      f32x4 acc = {0.f,0.f,0.f,0.f};                                            \
      _Pragma("unroll")                                                         \
      for (int kc = 0; kc < 8; ++kc){                                           \
        const bf16x8 af = *(const bf16x8*)&AfYhL[((my*10+kc)*64 + l)*8];        \
        acc = mfma16(af, wfr[kc], acc);                                         \
      }                                                                         \
      { const bf16x8 af8 = *(const bf16x8*)&AfYhL[((my*10+8)*64 + l)*8];        \
        const bf16x8 af9 = *(const bf16x8*)&AfYhL[((my*10+9)*64 + l)*8];        \
        acc = mfma16(af8, uf0, acc); acc = mfma16(af9, uf1, acc); }             \
      *(float4*)&yrow[my*16 + 4*lh] = make_float4(acc[0],acc[1],acc[2],acc[3]); \
    } }

  #pragma unroll 1
  for (int s = 0; s < 8; ++s){
    const int t = ch*8 + s;
    bf16x8 uf0, uf1;
    {
      union { ushort_t us[8]; bf16x8 v; } cv;
      cv.us[0]=f2bf(ua.x); cv.us[1]=f2bf(ua.y); cv.us[2]=f2bf(ua.z); cv.us[3]=f2bf(ua.w);
      cv.us[4]=f2bf(ub.x); cv.us[5]=f2bf(ub.y); cv.us[6]=f2bf(ub.z); cv.us[7]=f2bf(ub.w);
      uf0 = cv.v;
      cv.us[0]=f2bf(uc.x); cv.us[1]=f2bf(uc.y); cv.us[2]=f2bf(uc.z); cv.us[3]=f2bf(uc.w);
      cv.us[4]=0; cv.us[5]=0; cv.us[6]=0; cv.us[7]=0;
      uf1 = cv.v;
    }
    if (s < 7){
      const float* Ut = Ucol + (size_t)(t+1)*TS;
      ua = *(const float4*)&Ut[4*lh]; ub = *(const float4*)&Ut[16+4*lh]; uc = *(const float4*)&Ut[32+4*lh];
    }
    #pragma unroll
    for (int it = 0; it < 16; ++it){
      const bf16x8 a0 = *(const bf16x8*)&LwsL[((it*2+0)*64 + l)*8];
      const bf16x8 a1 = *(const bf16x8*)&LwsL[((it*2+1)*64 + l)*8];
      const float4 lv = *(const float4*)&lamL[32*(it>>1) + 16*(it&1) + 4*lh];
      f32x4 acc = {0.f,0.f,0.f,0.f};
      acc = mfma16(a0, uf0, acc);
      acc = mfma16(a1, uf1, acc);
      const int e0 = 8*(it>>1) + 4*(it&1);
      w[e0+0] = lv.x*w[e0+0] + acc[0];
      w[e0+1] = lv.y*w[e0+1] + acc[1];
      w[e0+2] = lv.z*w[e0+2] + acc[2];
      w[e0+3] = lv.w*w[e0+3] + acc[3];
    }
    bf16x8 wfr[8];
    #pragma unroll
    for (int kc = 0; kc < 8; ++kc){
      union { ushort_t us[8]; bf16x8 v; } cv;
      #pragma unroll
      for (int j = 0; j < 8; ++j) cv.us[j] = f2bf(w[8*kc + j]);
      wfr[kc] = cv.v;
    }
    if (h == 0){
      ZLOOP(0);
      YLOOP(0, 4);
    } else {
      ZLOOP(1);
      YLOOP(64, 1);
    }
  }
#undef ZLOOP
#undef YLOOP
}

// ---------------- launcher: 7 launches (was 11) ----------------
extern "C" void kernel_launch(void* const* d_in, const int* in_sizes, int n_in,
                              void* d_out, int out_size, void* d_ws, size_t ws_size,
                              hipStream_t stream){
  const float* z0  = (const float*)d_in[0];
  const float* dt  = (const float*)d_in[2];
  const float* U   = (const float*)d_in[3];
  const float* eig = (const float*)d_in[4];
  const float* V   = (const float*)d_in[5];
  const float* L   = (const float*)d_in[6];
  const float* C   = (const float*)d_in[7];
  const float* Dm  = (const float*)d_in[8];
  float* outZ = (float*)d_out;
  float* outY = outZ + (size_t)T_*B_*D_;

  char* ws = (char*)d_ws;
  float* Xa    = (float*)(ws + 0);        // W = V^2, then reused as VinvT
  float* Xb    = (float*)(ws + 262144);   // X1
  float* Tt    = (float*)(ws + 524288);   // T = V@X1
  float* Lw    = (float*)(ws + 786432);
  float* Cw    = (float*)(ws + 835584);
  float* lam   = (float*)(ws + 917504);
  float* dVd   = (float*)(ws + 918528);
  ushort_t* Af   = (ushort_t*)(ws + 919552);
  ushort_t* Lws  = (ushort_t*)(ws + 1134592);
  ushort_t* Wchk = (ushort_t*)(ws + 1167360);
  if (ws_size < 17944576u) return;

  k_pre   <<<337,256,0,stream>>>(V, eig, C, /*W=*/Xa, Cw, lam, dVd);
  k_x1    <<<256,256,0,stream>>>(V, /*W=*/Xa, /*X1=*/Xb);
  k_mm_mul<<<256,256,0,stream>>>(V, Xb, Tt);
  k_x2    <<<256,256,0,stream>>>(Xb, Tt, L, dt, /*VinvT=*/Xa, Lw);
  k_prep2 <<<342,256,0,stream>>>(z0, /*VinvT=*/Xa, Lw, V, Cw, Dm, dt, Wchk, Lws, Af);
  k_scan  <<<128,256,0,stream>>>(U, Lws, lam, Wchk);
  k_fused <<<1024,256,0,stream>>>(U, Af, Lws, lam, dVd, Wchk, outZ, outY);
}

// Round 11
// 262.045 us; speedup vs baseline: 2.0593x; 1.0674x over previous
//
#include <hip/hip_runtime.h>

#define D_   256
#define UD_  48
#define NO_  80
#define T_   128
#define B_   2048

typedef __bf16 bf16x8 __attribute__((ext_vector_type(8)));
typedef float  f32x4  __attribute__((ext_vector_type(4)));
typedef unsigned short ushort_t;

static __device__ __forceinline__ ushort_t f2bf(float f){
  return __builtin_bit_cast(ushort_t, (__bf16)f);
}
static __device__ __forceinline__ float bf2f(ushort_t u){
  union { unsigned int i; float f; } c; c.i = ((unsigned int)u) << 16; return c.f;
}
static __device__ __forceinline__ f32x4 mfma16(bf16x8 a, bf16x8 b, f32x4 c){
  return __builtin_amdgcn_mfma_f32_16x16x32_bf16(a, b, c, 0, 0, 0);
}

// ---------------- prep: 5 kernels (round-10 chain, unchanged) ----------------
// NS iter1 closed form: X1 = 4I - 6V + 4W - V@W, W = V^2. 2 NS iterations total.

__global__ void __launch_bounds__(256) k_pre(
    const float* __restrict__ V, const float* __restrict__ eig,
    const float* __restrict__ Cmat,
    float* __restrict__ W, float* __restrict__ Cw,
    float* __restrict__ lam, float* __restrict__ dVd){
  const int bid = blockIdx.x, tid = threadIdx.x;
  if (bid < 256){
    const float* Ar = V + bid*D_;
    float a0=0.f,a1=0.f,a2=0.f,a3=0.f;
    #pragma unroll 4
    for (int k = 0; k < D_; k += 4){
      a0 += Ar[k+0] * V[(k+0)*D_ + tid];
      a1 += Ar[k+1] * V[(k+1)*D_ + tid];
      a2 += Ar[k+2] * V[(k+2)*D_ + tid];
      a3 += Ar[k+3] * V[(k+3)*D_ + tid];
    }
    W[bid*D_ + tid] = (a0+a1)+(a2+a3);
  } else if (bid < 256 + NO_){
    const int n = bid - 256;
    float acc = 0.f;
    #pragma unroll 4
    for (int j = 0; j < D_; ++j) acc += Cmat[n*D_ + j] * V[j*D_ + tid];
    Cw[n*D_ + tid] = acc;
  } else {
    lam[tid] = 0.99f / (1.0f + expf(-eig[tid]));
    const float v = V[tid*D_ + tid];
    dVd[tid] = v - bf2f(f2bf(v));
  }
}

__global__ void __launch_bounds__(256) k_x1(
    const float* __restrict__ V, const float* __restrict__ W,
    float* __restrict__ X1){
  const int i = blockIdx.x, j = threadIdx.x;
  const float* Ar = V + i*D_;
  float a0=0.f,a1=0.f,a2=0.f,a3=0.f;
  #pragma unroll 4
  for (int k = 0; k < D_; k += 4){
    a0 += Ar[k+0] * W[(k+0)*D_ + j];
    a1 += Ar[k+1] * W[(k+1)*D_ + j];
    a2 += Ar[k+2] * W[(k+2)*D_ + j];
    a3 += Ar[k+3] * W[(k+3)*D_ + j];
  }
  X1[i*D_ + j] = (i == j ? 4.0f : 0.0f) - 6.0f*V[i*D_ + j] + 4.0f*W[i*D_ + j]
                 - ((a0+a1)+(a2+a3));
}

__global__ void __launch_bounds__(256) k_mm_mul(
    const float* __restrict__ A, const float* __restrict__ B,
    float* __restrict__ Cm){
  const int i = blockIdx.x, j = threadIdx.x;
  const float* Ar = A + i*D_;
  float a0=0.f,a1=0.f,a2=0.f,a3=0.f;
  #pragma unroll 4
  for (int k = 0; k < D_; k += 4){
    a0 += Ar[k+0] * B[(k+0)*D_ + j];
    a1 += Ar[k+1] * B[(k+1)*D_ + j];
    a2 += Ar[k+2] * B[(k+2)*D_ + j];
    a3 += Ar[k+3] * B[(k+3)*D_ + j];
  }
  Cm[i*D_ + j] = (a0+a1)+(a2+a3);
}

__global__ void __launch_bounds__(256) k_x2(
    const float* __restrict__ X1, const float* __restrict__ Tm,
    const float* __restrict__ Lmat, const float* __restrict__ dt,
    float* __restrict__ VinvT, float* __restrict__ Lw){
  __shared__ float row[256];
  const int i = blockIdx.x, j = threadIdx.x;
  const float* Xr = X1 + i*D_;
  float a0=0.f,a1=0.f,a2=0.f,a3=0.f;
  #pragma unroll 4
  for (int k = 0; k < D_; k += 4){
    a0 += Xr[k+0] * Tm[(k+0)*D_ + j];
    a1 += Xr[k+1] * Tm[(k+1)*D_ + j];
    a2 += Xr[k+2] * Tm[(k+2)*D_ + j];
    a3 += Xr[k+3] * Tm[(k+3)*D_ + j];
  }
  const float out = 2.0f*Xr[j] - ((a0+a1)+(a2+a3));
  VinvT[j*D_ + i] = out;
  row[j] = out;
  __syncthreads();
  if (j < UD_){
    float acc = 0.f;
    #pragma unroll 4
    for (int k = 0; k < D_; ++k) acc += row[k] * Lmat[k*UD_ + j];
    Lw[i*UD_ + j] = acc * dt[0];
  }
}

__global__ void __launch_bounds__(256) k_prep2(
    const float* __restrict__ z0, const float* __restrict__ VinvT,
    const float* __restrict__ Lw, const float* __restrict__ V,
    const float* __restrict__ Cw, const float* __restrict__ Dmat,
    const float* __restrict__ dt,
    ushort_t* __restrict__ Wchk, ushort_t* __restrict__ Lws,
    ushort_t* __restrict__ Af){
  __shared__ float zr[8][256];
  const int bid = blockIdx.x, tid = threadIdx.x;
  if (bid < 256){
    const int b0 = bid * 8;
    #pragma unroll
    for (int r = 0; r < 8; ++r) zr[r][tid] = z0[(size_t)(b0+r)*D_ + tid];
    __syncthreads();
    float acc[8] = {0.f,0.f,0.f,0.f,0.f,0.f,0.f,0.f};
    #pragma unroll 4
    for (int j = 0; j < D_; ++j){
      const float vj = VinvT[j*D_ + tid];
      #pragma unroll
      for (int r = 0; r < 8; ++r) acc[r] += zr[r][j] * vj;
    }
    #pragma unroll
    for (int r = 0; r < 8; ++r)
      Wchk[(size_t)(b0+r)*D_ + tid] = f2bf(acc[r]);
  } else if (bid < 288){
    const int f = bid - 256;
    if (tid < 64){
      const int l = tid, lm = l & 15, lh = l >> 4;
      const int it = f >> 1, kc2 = f & 1;
      const int ig = it*16 + lm;
      #pragma unroll
      for (int j = 0; j < 8; ++j){
        const int k = 32*kc2 + 4*lh + (j & 3) + 16*(j >> 2);
        Lws[(f*64 + l)*8 + j] = f2bf(k < UD_ ? Lw[ig*UD_ + k] : 0.f);
      }
    }
  } else {
    const int v = (bid - 288)*4 + (tid >> 6);
    if (v < 210){
      const int mt = v / 10, kc = v % 10;
      const int l = tid & 63, lm = l & 15, lh = l >> 4;
      const float dts = dt[0];
      #pragma unroll
      for (int j = 0; j < 8; ++j){
        const int k = 32*kc + 4*lh + (j & 3) + 16*(j >> 2);
        float val = 0.f;
        if (mt < 16){
          if (kc < 8) val = V[(mt*16 + lm)*D_ + k];
        } else {
          const int n = (mt - 16)*16 + lm;
          if (kc < 8) val = Cw[n*D_ + k];
          else { const int ku = k - 256; if (ku < UD_) val = dts * Dmat[n*UD_ + ku]; }
        }
        Af[((size_t)(mt*10 + kc)*64 + l)*8 + j] = f2bf(val);
      }
    }
  }
}

// ---------------- two-level parallel scan (diagonal Lambda) ----------------
// w_t = L w_{t-1} + f_t splits chunk-wise: boundary W_ch = L^8 W_{ch-1} + c_{ch-1},
// c_j = local scan of chunk j from ZERO state -- fully parallel over the 15 chunks.
// Replaces the 128-step sequential k_scan (2 waves/CU, latency-bound, ~100us).

#define LSCAN_STEP(UA, UB, UC) do {                                             \
  union { ushort_t us[8]; bf16x8 v; } c0, c1;                                   \
  c0.us[0]=f2bf((UA).x); c0.us[1]=f2bf((UA).y); c0.us[2]=f2bf((UA).z); c0.us[3]=f2bf((UA).w); \
  c0.us[4]=f2bf((UB).x); c0.us[5]=f2bf((UB).y); c0.us[6]=f2bf((UB).z); c0.us[7]=f2bf((UB).w); \
  c1.us[0]=f2bf((UC).x); c1.us[1]=f2bf((UC).y); c1.us[2]=f2bf((UC).z); c1.us[3]=f2bf((UC).w); \
  c1.us[4]=0; c1.us[5]=0; c1.us[6]=0; c1.us[7]=0;                               \
  _Pragma("unroll")                                                             \
  for (int q = 0; q < 4; ++q){                                                  \
    f32x4 acc = {0.f,0.f,0.f,0.f};                                              \
    acc = mfma16(lwf[q*2+0], c0.v, acc);                                        \
    acc = mfma16(lwf[q*2+1], c1.v, acc);                                        \
    _Pragma("unroll")                                                           \
    for (int r = 0; r < 4; ++r) w[q*4+r] = lamr[q*4+r]*w[q*4+r] + acc[r];       \
  }                                                                             \
} while(0)

// Phase A: 1920 blocks = 15 ch x 128 bq; block = 16 batch rows, full 256 dims
// (wave owns 4 it-blocks). Scans its chunk's 8 steps from w=0, writes c_ch
// into the Wchk[ch+1] slot (bf16).
__global__ void __launch_bounds__(256) k_scanA(const float* __restrict__ U,
    const ushort_t* __restrict__ Lws, const float* __restrict__ lam,
    ushort_t* __restrict__ Wchk){
  const int tid = threadIdx.x;
  const int wid = tid >> 6, l = tid & 63;
  const int lm = l & 15, lh = l >> 4;
  const int ch = blockIdx.x >> 7;        // 0..14
  const int bq = blockIdx.x & 127;
  const int row = bq*16 + lm;
  const int itb = wid*4;

  bf16x8 lwf[8];
  #pragma unroll
  for (int q = 0; q < 4; ++q)
    #pragma unroll
    for (int c = 0; c < 2; ++c)
      lwf[q*2 + c] = *(const bf16x8*)(Lws + ((size_t)(((itb+q)*2 + c)*64 + l))*8);

  float lamr[16], w[16];
  #pragma unroll
  for (int q = 0; q < 4; ++q){
    const int i = (itb+q)*16 + 4*lh;
    const float4 lv = *(const float4*)&lam[i];
    lamr[q*4+0]=lv.x; lamr[q*4+1]=lv.y; lamr[q*4+2]=lv.z; lamr[q*4+3]=lv.w;
    w[q*4+0]=0.f; w[q*4+1]=0.f; w[q*4+2]=0.f; w[q*4+3]=0.f;
  }

  const size_t TS = (size_t)B_ * UD_;
  const float* Urow = U + ((size_t)(ch*8)*B_ + row) * UD_;
  float4 Aa, Ab, Ac, Ba, Bb, Bc;
  Aa = *(const float4*)&Urow[4*lh]; Ab = *(const float4*)&Urow[16+4*lh]; Ac = *(const float4*)&Urow[32+4*lh];
  { const float* Up = Urow + TS;
    Ba = *(const float4*)&Up[4*lh]; Bb = *(const float4*)&Up[16+4*lh]; Bc = *(const float4*)&Up[32+4*lh]; }

  #pragma unroll
  for (int tt = 0; tt < 4; ++tt){
    LSCAN_STEP(Aa, Ab, Ac);
    if (tt < 3){
      const float* Up = Urow + (size_t)(2*tt+2)*TS;
      Aa = *(const float4*)&Up[4*lh]; Ab = *(const float4*)&Up[16+4*lh]; Ac = *(const float4*)&Up[32+4*lh];
    }
    LSCAN_STEP(Ba, Bb, Bc);
    if (tt < 3){
      const float* Up = Urow + (size_t)(2*tt+3)*TS;
      Ba = *(const float4*)&Up[4*lh]; Bb = *(const float4*)&Up[16+4*lh]; Bc = *(const float4*)&Up[32+4*lh];
    }
  }
  #pragma unroll
  for (int q = 0; q < 4; ++q){
    const int i = (itb+q)*16 + 4*lh;
    ushort4 o; o.x=f2bf(w[q*4+0]); o.y=f2bf(w[q*4+1]); o.z=f2bf(w[q*4+2]); o.w=f2bf(w[q*4+3]);
    *(ushort4*)(Wchk + ((size_t)(ch+1)*B_ + row)*D_ + i) = o;
  }
}

// Phase B: in-place prefix combine over the 16 checkpoints.
// W_{j+1} = lam^8 * W_j + c_j; running W stays f32 in registers.
// 128 blocks x 256 thr; block = 16 batch rows, thread = one dim.
__global__ void __launch_bounds__(256) k_scanB(const float* __restrict__ lam,
    ushort_t* __restrict__ Wchk){
  const int d = threadIdx.x;
  const int b0 = blockIdx.x * 16;
  float l2 = lam[d]; l2 = l2*l2;
  float l8 = l2*l2;  l8 = l8*l8;        // lam^8
  float W[16];
  #pragma unroll
  for (int r = 0; r < 16; ++r)
    W[r] = bf2f(Wchk[(size_t)(b0+r)*D_ + d]);
  #pragma unroll 1
  for (int j = 0; j < 15; ++j){
    ushort_t* slot = Wchk + (size_t)(j+1)*B_*D_;
    #pragma unroll
    for (int r = 0; r < 16; ++r){
      const float c = bf2f(slot[(size_t)(b0+r)*D_ + d]);
      W[r] = l8*W[r] + c;
      slot[(size_t)(b0+r)*D_ + d] = f2bf(W[r]);
    }
  }
}

// ---------------- fused replay + output GEMM (round-6 version, F~144us) ----------------
// Unpaired (rounds 8/9: step-pairing loses). 1024 blocks = 32 bq x 16 ch x 2 h
// (h low bit). Y split 64/16. LDS h-max 158208 B.
__global__ void __launch_bounds__(256) k_fused(
    const float* __restrict__ U, const ushort_t* __restrict__ Af,
    const ushort_t* __restrict__ Lws, const float* __restrict__ lam,
    const float* __restrict__ dVd, const ushort_t* __restrict__ Wchk,
    float* __restrict__ outZ, float* __restrict__ outY){
  __shared__ __align__(16) ushort_t AfZhL[8*8*512];   // 65536 B
  __shared__ __align__(16) ushort_t LwsL[32*512];     // 32768 B
  __shared__ __align__(16) ushort_t AfYhL[40*512];    // 40960 B
  __shared__ __align__(16) float    trbZ[4][16][68];  // 17408 B
  __shared__ __align__(16) float    dVdL[128];        // 512 B
  __shared__ __align__(16) float    lamL[256];        // 1024 B

  const int tid = threadIdx.x;
  const int bid = blockIdx.x;
  const int h  = bid & 1;
  const int ch = (bid >> 1) & 15;
  const int bq = bid >> 5;
  const int wid = tid >> 6, l = tid & 63;
  const int lm = l & 15, lh = l >> 4;
  const int col0 = bq*64 + wid*16;
  const int col = col0 + lm;

  // one-time staging
  {
    const uint4* gsrc = (const uint4*)Af;
    uint4* dz = (uint4*)AfZhL;
    #pragma unroll
    for (int r = 0; r < 16; ++r){
      const int i = r*256 + tid;
      const int f = i >> 6, l4 = i & 63;
      const int mi8 = f >> 3, kc = f & 7;
      dz[i] = gsrc[(size_t)((h*8 + mi8)*10 + kc)*64 + l4];
    }
    uint4* dy = (uint4*)AfYhL;
    const int nY = h ? 640 : 2560;
    const int sb = 16 + (h ? 4 : 0);
    #pragma unroll
    for (int r = 0; r < 10; ++r){
      const int i = r*256 + tid;
      if (i < nY){
        const int f = i >> 6, l4 = i & 63;
        const int myl = f / 10, j = f % 10;
        dy[i] = gsrc[(size_t)((sb + myl)*10 + j)*64 + l4];
      }
    }
    const uint4* ls = (const uint4*)Lws;
    uint4* ld = (uint4*)LwsL;
    #pragma unroll
    for (int r = 0; r < 8; ++r) ld[r*256 + tid] = ls[r*256 + tid];
    if (tid < 32) ((float4*)dVdL)[tid] = ((const float4*)(dVd + h*128))[tid];
    else if (tid < 96) ((float4*)lamL)[tid-32] = ((const float4*)lam)[tid-32];
  }

  // boundary w
  float w[64];
  #pragma unroll
  for (int kc = 0; kc < 8; ++kc)
    #pragma unroll
    for (int hh = 0; hh < 2; ++hh){
      const int i = 32*kc + 16*hh + 4*lh;
      const ushort4 wu = *(const ushort4*)(Wchk + ((size_t)ch*B_ + col)*D_ + i);
      const int e = 8*kc + 4*hh;
      w[e+0]=bf2f(wu.x); w[e+1]=bf2f(wu.y); w[e+2]=bf2f(wu.z); w[e+3]=bf2f(wu.w);
    }

  // u prefetch
  const size_t TS = (size_t)B_ * UD_;
  const float* Ucol = U + (size_t)col * UD_;
  float4 ua, ub, uc;
  {
    const float* Ut = Ucol + (size_t)(ch*8)*TS;
    ua = *(const float4*)&Ut[4*lh]; ub = *(const float4*)&Ut[16+4*lh]; uc = *(const float4*)&Ut[32+4*lh];
  }

  __syncthreads();   // the only block-wide barrier

#define ZLOOP(HH)                                                               \
  { float* zbase = outZ + ((size_t)t*B_ + col0)*D_ + (HH)*128;                  \
    _Pragma("unroll")                                                           \
    for (int g = 0; g < 2; ++g){                                                \
      _Pragma("unroll")                                                         \
      for (int mi = 0; mi < 4; ++mi){                                           \
        const int mi8 = g*4 + mi;                                               \
        f32x4 acc = {0.f,0.f,0.f,0.f};                                          \
        _Pragma("unroll")                                                       \
        for (int kc = 0; kc < 8; ++kc){                                         \
          const bf16x8 af = *(const bf16x8*)&AfZhL[((mi8*8+kc)*64 + l)*8];      \
          acc = mfma16(af, wfr[kc], acc);                                       \
        }                                                                       \
        const float4 dv = *(const float4*)&dVdL[mi8*16 + 4*lh];                 \
        acc[0] += dv.x * (float)wfr[((HH)*8+mi8)>>1][0 + 4*(mi8&1)];            \
        acc[1] += dv.y * (float)wfr[((HH)*8+mi8)>>1][1 + 4*(mi8&1)];            \
        acc[2] += dv.z * (float)wfr[((HH)*8+mi8)>>1][2 + 4*(mi8&1)];            \
        acc[3] += dv.w * (float)wfr[((HH)*8+mi8)>>1][3 + 4*(mi8&1)];            \
        *(float4*)&trbZ[wid][lm][mi*16 + 4*lh] = make_float4(acc[0],acc[1],acc[2],acc[3]); \
      }                                                                         \
      __builtin_amdgcn_wave_barrier();                                          \
      _Pragma("unroll")                                                         \
      for (int j = 0; j < 4; ++j){                                              \
        const int r_ = j*4 + (l >> 4), c16 = l & 15;                            \
        const float4 v = *(const float4*)&trbZ[wid][r_][4*c16];                 \
        *(float4*)&zbase[(size_t)r_*D_ + g*64 + 4*c16] = v;                     \
      }                                                                         \
      __builtin_amdgcn_wave_barrier();                                          \
    } }

#define YLOOP(COFF, NMY)                                                        \
  { float* yrow = outY + ((size_t)t*B_ + col)*NO_ + (COFF);                     \
    _Pragma("unroll")                                                           \
    for (int my = 0; my < (NMY); ++my){                                         \
      f32x4 acc = {0.f,0.f,0.f,0.f};                                            \
      _Pragma("unroll")                                                         \
      for (int kc = 0; kc < 8; ++kc){                                           \
        const bf16x8 af = *(const bf16x8*)&AfYhL[((my*10+kc)*64 + l)*8];        \
        acc = mfma16(af, wfr[kc], acc);                                         \
      }                                                                         \
      { const bf16x8 af8 = *(const bf16x8*)&AfYhL[((my*10+8)*64 + l)*8];        \
        const bf16x8 af9 = *(const bf16x8*)&AfYhL[((my*10+9)*64 + l)*8];        \
        acc = mfma16(af8, uf0, acc); acc = mfma16(af9, uf1, acc); }             \
      *(float4*)&yrow[my*16 + 4*lh] = make_float4(acc[0],acc[1],acc[2],acc[3]); \
    } }

  #pragma unroll 1
  for (int s = 0; s < 8; ++s){
    const int t = ch*8 + s;
    bf16x8 uf0, uf1;
    {
      union { ushort_t us[8]; bf16x8 v; } cv;
      cv.us[0]=f2bf(ua.x); cv.us[1]=f2bf(ua.y); cv.us[2]=f2bf(ua.z); cv.us[3]=f2bf(ua.w);
      cv.us[4]=f2bf(ub.x); cv.us[5]=f2bf(ub.y); cv.us[6]=f2bf(ub.z); cv.us[7]=f2bf(ub.w);
      uf0 = cv.v;
      cv.us[0]=f2bf(uc.x); cv.us[1]=f2bf(uc.y); cv.us[2]=f2bf(uc.z); cv.us[3]=f2bf(uc.w);
      cv.us[4]=0; cv.us[5]=0; cv.us[6]=0; cv.us[7]=0;
      uf1 = cv.v;
    }
    if (s < 7){
      const float* Ut = Ucol + (size_t)(t+1)*TS;
      ua = *(const float4*)&Ut[4*lh]; ub = *(const float4*)&Ut[16+4*lh]; uc = *(const float4*)&Ut[32+4*lh];
    }
    #pragma unroll
    for (int it = 0; it < 16; ++it){
      const bf16x8 a0 = *(const bf16x8*)&LwsL[((it*2+0)*64 + l)*8];
      const bf16x8 a1 = *(const bf16x8*)&LwsL[((it*2+1)*64 + l)*8];
      const float4 lv = *(const float4*)&lamL[32*(it>>1) + 16*(it&1) + 4*lh];
      f32x4 acc = {0.f,0.f,0.f,0.f};
      acc = mfma16(a0, uf0, acc);
      acc = mfma16(a1, uf1, acc);
      const int e0 = 8*(it>>1) + 4*(it&1);
      w[e0+0] = lv.x*w[e0+0] + acc[0];
      w[e0+1] = lv.y*w[e0+1] + acc[1];
      w[e0+2] = lv.z*w[e0+2] + acc[2];
      w[e0+3] = lv.w*w[e0+3] + acc[3];
    }
    bf16x8 wfr[8];
    #pragma unroll
    for (int kc = 0; kc < 8; ++kc){
      union { ushort_t us[8]; bf16x8 v; } cv;
      #pragma unroll
      for (int j = 0; j < 8; ++j) cv.us[j] = f2bf(w[8*kc + j]);
      wfr[kc] = cv.v;
    }
    if (h == 0){
      ZLOOP(0);
      YLOOP(0, 4);
    } else {
      ZLOOP(1);
      YLOOP(64, 1);
    }
  }
#undef ZLOOP
#undef YLOOP
}

// ---------------- launcher: 8 launches ----------------
extern "C" void kernel_launch(void* const* d_in, const int* in_sizes, int n_in,
                              void* d_out, int out_size, void* d_ws, size_t ws_size,
                              hipStream_t stream){
  const float* z0  = (const float*)d_in[0];
  const float* dt  = (const float*)d_in[2];
  const float* U   = (const float*)d_in[3];
  const float* eig = (const float*)d_in[4];
  const float* V   = (const float*)d_in[5];
  const float* L   = (const float*)d_in[6];
  const float* C   = (const float*)d_in[7];
  const float* Dm  = (const float*)d_in[8];
  float* outZ = (float*)d_out;
  float* outY = outZ + (size_t)T_*B_*D_;

  char* ws = (char*)d_ws;
  float* Xa    = (float*)(ws + 0);        // W = V^2, then reused as VinvT
  float* Xb    = (float*)(ws + 262144);   // X1
  float* Tt    = (float*)(ws + 524288);   // T = V@X1
  float* Lw    = (float*)(ws + 786432);
  float* Cw    = (float*)(ws + 835584);
  float* lam   = (float*)(ws + 917504);
  float* dVd   = (float*)(ws + 918528);
  ushort_t* Af   = (ushort_t*)(ws + 919552);
  ushort_t* Lws  = (ushort_t*)(ws + 1134592);
  ushort_t* Wchk = (ushort_t*)(ws + 1167360);
  if (ws_size < 17944576u) return;

  k_pre   <<<337,256,0,stream>>>(V, eig, C, /*W=*/Xa, Cw, lam, dVd);
  k_x1    <<<256,256,0,stream>>>(V, /*W=*/Xa, /*X1=*/Xb);
  k_mm_mul<<<256,256,0,stream>>>(V, Xb, Tt);
  k_x2    <<<256,256,0,stream>>>(Xb, Tt, L, dt, /*VinvT=*/Xa, Lw);
  k_prep2 <<<342,256,0,stream>>>(z0, /*VinvT=*/Xa, Lw, V, Cw, Dm, dt, Wchk, Lws, Af);
  k_scanA <<<1920,256,0,stream>>>(U, Lws, lam, Wchk);
  k_scanB <<<128,256,0,stream>>>(lam, Wchk);
  k_fused <<<1024,256,0,stream>>>(U, Af, Lws, lam, dVd, Wchk, outZ, outY);
}